// Round 6
// baseline (542.101 us; speedup 1.0000x reference)
//
#include <hip/hip_runtime.h>
#include <math.h>

#define TOKENS 2048
#define DIM 1024
#define NHEADS 16
#define HEADDIM 64
#define NEXP 32
#define EDIM 128
#define TOPK 8
#define DSHARED 2048
#define RSF_ 2.5f
#define EPS_ 1e-6f

using bf8  = __attribute__((ext_vector_type(8))) short;   // 8 bf16 in 4 VGPRs
using f32x4 = __attribute__((ext_vector_type(4))) float;  // MFMA accumulator

__device__ __forceinline__ short f2bf(float f) {
    unsigned u = __float_as_uint(f);
    unsigned r = (u + 0x7fffu + ((u >> 16) & 1u)) >> 16;
    return (short)r;
}
__device__ __forceinline__ float bf2f(short s) {
    return __uint_as_float(((unsigned)(unsigned short)s) << 16);
}

// Direct global->LDS DMA, 16B per lane. LDS dest = wave-uniform base + lane*16.
__device__ __forceinline__ void async16(const short* g, const short* l) {
    __builtin_amdgcn_global_load_lds(
        (const __attribute__((address_space(1))) void*)(unsigned long long)g,
        (__attribute__((address_space(3))) void*)(unsigned)(unsigned long long)l,
        16, 0, 0);
}

// ---------------- RMSNorm: one block per token, bf16 output ----------------
__global__ __launch_bounds__(256) void rmsnorm_kernel(const float* __restrict__ x,
                                                      const float* __restrict__ w,
                                                      short* __restrict__ out) {
    int row = blockIdx.x;
    const float* xr = x + (long long)row * DIM;
    int t = threadIdx.x;
    float4 xv = ((const float4*)xr)[t];
    float ss = xv.x*xv.x + xv.y*xv.y + xv.z*xv.z + xv.w*xv.w;
    #pragma unroll
    for (int off = 32; off; off >>= 1) ss += __shfl_down(ss, off);
    __shared__ float warps[4];
    if ((t & 63) == 0) warps[t >> 6] = ss;
    __syncthreads();
    float tot = warps[0] + warps[1] + warps[2] + warps[3];
    float scale = rsqrtf(tot / (float)DIM + EPS_);
    float4 wv = ((const float4*)w)[t];
    short4 o;
    o.x = f2bf(xv.x * scale * wv.x);
    o.y = f2bf(xv.y * scale * wv.y);
    o.z = f2bf(xv.z * scale * wv.z);
    o.w = f2bf(xv.w * scale * wv.w);
    ((short4*)(out + (long long)row * DIM))[t] = o;
}

// ---------------- Transpose + convert: fp32 in[K][N] -> bf16 out[N][K] ----------------
__global__ __launch_bounds__(256) void tconv(const float* __restrict__ in, long long sin,
                                             short* __restrict__ out, long long sout,
                                             int K, int N) {
    in  += (long long)blockIdx.z * sin;
    out += (long long)blockIdx.z * sout;
    __shared__ float t[32][33];
    int n0 = blockIdx.x * 32, k0 = blockIdx.y * 32;
    int tx = threadIdx.x & 31, ty = threadIdx.x >> 5;  // ty 0..7
    #pragma unroll
    for (int r = ty; r < 32; r += 8)
        t[r][tx] = in[(long long)(k0 + r) * N + n0 + tx];
    __syncthreads();
    #pragma unroll
    for (int r = ty; r < 32; r += 8)
        out[(long long)(n0 + r) * K + k0 + tx] = f2bf(t[tx][r]);
}

// W2 [e][d][h] fp32 -> bf16 [d][(e*128+h)]
__global__ void w2conv(const float* __restrict__ in, short* __restrict__ out) {
    long long i = (long long)blockIdx.x * 256 + threadIdx.x;  // 4M
    int e = (int)(i >> 17);
    int d = (int)(i >> 7) & 1023;
    int h = (int)(i & 127);
    out[(long long)d * (NEXP * EDIM) + e * EDIM + h] = f2bf(in[i]);
}

// ---------------- bf16 MFMA GEMM: C[M][N] = A[M][K] @ Bt[N][K]^T ----------------
// 128x128 tile, BK=64, XOR-swizzled LDS (conflict-free ds_read_b128),
// async global->LDS staging.
// MODE 0: f32 store, z = batch.  MODE 1: f32 atomicAdd, z = K-split index.
// MODE 2: bf16 store, z = batch.
template<int MODE>
__global__ __launch_bounds__(256) void gemm_bf16(const short* __restrict__ A, int lda, long long sA,
                                                 const short* __restrict__ Bt, int ldb, long long sBt,
                                                 void* __restrict__ Cv, int ldc, long long sC,
                                                 int M, int N, int K) {
    int koff = 0, Ksub = K;
    if (MODE == 1) {
        Ksub = K / gridDim.z;
        koff = blockIdx.z * Ksub;
    } else {
        A  += (long long)blockIdx.z * sA;
        Bt += (long long)blockIdx.z * sBt;
    }
    float* Cf = (float*)Cv;
    short* Cs = (short*)Cv;
    if (MODE != 1) { Cf += (long long)blockIdx.z * sC; Cs += (long long)blockIdx.z * sC; }
    const int m0 = blockIdx.y * 128, n0 = blockIdx.x * 128;
    __shared__ short As[128 * 64];
    __shared__ short Bs[128 * 64];
    const int tid = threadIdx.x, lane = tid & 63, w = tid >> 6;
    const int wm = (w >> 1) * 64, wn = (w & 1) * 64;
    // DMA: wave w stages rows [w*32, w*32+32). Instr c covers rows c*8+drow.
    // Source col XOR-swizzled so LDS(r, j16) holds global chunk j16^(r&7).
    const int drow = lane >> 3;                  // 0..7
    const int dcol = ((lane & 7) ^ drow) * 8;    // swizzled 16B-chunk col, shorts
    const short* ag = A + (long long)(m0 + w * 32 + drow) * lda + koff + dcol;
    const short* bg = Bt + (long long)(n0 + w * 32 + drow) * ldb + koff + dcol;
    const short* lA = As + w * 32 * 64;
    const short* lB = Bs + w * 32 * 64;
    f32x4 acc[4][4];
    #pragma unroll
    for (int i = 0; i < 4; ++i)
        #pragma unroll
        for (int j = 0; j < 4; ++j) { f32x4 z = {0.f, 0.f, 0.f, 0.f}; acc[i][j] = z; }
    const int ra = lane & 15, quad = lane >> 4;
    // fragment chunk (h*4+quad) lives at swizzled col (h*4+quad)^(ra&7)
    const int fs0 = ((quad + 0) ^ (ra & 7)) * 8;
    const int fs1 = ((quad + 4) ^ (ra & 7)) * 8;
    for (int k0 = 0; k0 < Ksub; k0 += 64) {
        #pragma unroll
        for (int c = 0; c < 4; ++c) {
            async16(ag + (long long)(c * 8) * lda + k0, lA + c * 512);
            async16(bg + (long long)(c * 8) * ldb + k0, lB + c * 512);
        }
        __syncthreads();   // drains vmcnt -> tiles resident
        #pragma unroll
        for (int h = 0; h < 2; ++h) {
            const int fs = h ? fs1 : fs0;
            bf8 af[4], bfv[4];
            #pragma unroll
            for (int i = 0; i < 4; ++i) af[i]  = *(const bf8*)(As + (wm + i * 16 + ra) * 64 + fs);
            #pragma unroll
            for (int j = 0; j < 4; ++j) bfv[j] = *(const bf8*)(Bs + (wn + j * 16 + ra) * 64 + fs);
            #pragma unroll
            for (int i = 0; i < 4; ++i)
                #pragma unroll
                for (int j = 0; j < 4; ++j)
                    acc[i][j] = __builtin_amdgcn_mfma_f32_16x16x32_bf16(af[i], bfv[j], acc[i][j], 0, 0, 0);
        }
        __syncthreads();   // reads done before next DMA overwrites
    }
    const int cr = quad * 4, cc = ra;
    #pragma unroll
    for (int i = 0; i < 4; ++i) {
        #pragma unroll
        for (int r = 0; r < 4; ++r) {
            int row = m0 + wm + i * 16 + cr + r;
            long long base = (long long)row * ldc + n0 + wn + cc;
            #pragma unroll
            for (int j = 0; j < 4; ++j) {
                float v = acc[i][j][r];
                if (MODE == 0) Cf[base + j * 16] = v;
                if (MODE == 1) atomicAdd(Cf + base + j * 16, v);
                if (MODE == 2) Cs[base + j * 16] = f2bf(v);
            }
        }
    }
}

// ---------------- zero / copy helpers (float4-vectorized) ----------------
__global__ void zero_f32(float* __restrict__ p) {
    long long i = (long long)blockIdx.x * 256 + threadIdx.x;
    ((float4*)p)[i] = make_float4(0.f, 0.f, 0.f, 0.f);
}
__global__ void copy_f32(float* __restrict__ dst, const float* __restrict__ src) {
    long long i = (long long)blockIdx.x * 256 + threadIdx.x;
    ((float4*)dst)[i] = ((const float4*)src)[i];
}

// ---------------- QKV post: split heads, l2norm(q,k), RoPE -> bf16 [h][s][64] ----------------
__global__ __launch_bounds__(256) void qkv_post(const float* __restrict__ qkv,
                                                short* __restrict__ q,
                                                short* __restrict__ k) {
    int lane = threadIdx.x & 63;
    int sh = blockIdx.x * 4 + (threadIdx.x >> 6);
    int s = sh >> 4;
    int h = sh & 15;
    const float* base = qkv + (long long)s * 3 * DIM;
    float qv = base[h * HEADDIM + lane];
    float kv = base[DIM + h * HEADDIM + lane];
    float qs = qv * qv, ks = kv * kv;
    #pragma unroll
    for (int off = 32; off; off >>= 1) {
        qs += __shfl_xor(qs, off);
        ks += __shfl_xor(ks, off);
    }
    qv /= fmaxf(sqrtf(qs), EPS_);
    kv /= fmaxf(sqrtf(ks), EPS_);
    int i = lane & 31;
    float f = (float)s * powf(10000.0f, -(float)i / 32.0f);
    float c = cosf(f), sn = sinf(f);
    float qo = __shfl_xor(qv, 32);
    float ko = __shfl_xor(kv, 32);
    float sgn = (lane < 32) ? sn : -sn;
    float qr = qv * c + qo * sgn;
    float kr = kv * c + ko * sgn;
    long long o = ((long long)h * TOKENS + s) * HEADDIM + lane;
    q[o] = f2bf(qr);
    k[o] = f2bf(kr);
}

// ---------------- V transpose: qkv fp32 [s][3D] -> vt bf16 [h][64][2048] ----------------
__global__ __launch_bounds__(256) void vtrans(const float* __restrict__ qkv,
                                              short* __restrict__ vt) {
    int h = blockIdx.z;
    int s0 = blockIdx.x * 32, d0 = blockIdx.y * 32;
    __shared__ float t[32][33];
    int tx = threadIdx.x & 31, ty = threadIdx.x >> 5;
    #pragma unroll
    for (int r = ty; r < 32; r += 8)
        t[r][tx] = qkv[(long long)(s0 + r) * (3 * DIM) + 2 * DIM + h * HEADDIM + d0 + tx];
    __syncthreads();
    #pragma unroll
    for (int r = ty; r < 32; r += 8)
        vt[((long long)h * HEADDIM + d0 + r) * TOKENS + s0 + tx] = f2bf(t[tx][r]);
}

// ---------------- MFMA flash attention, wave-autonomous (no barriers) ----------------
// One wave = 16 q-rows of one head; K/V fragments loaded straight from global
// (B-fragment = 8 contiguous bf16/lane). qk-norm bounds |s|<=~0.13 so no
// running max / rescale is needed: p = exp(s), l accumulated per-lane,
// reduced once at the end. P goes through wave-private LDS (stride 68,
// bank-balanced) for the C-layout -> A-layout transform.
#define PLD 68
__global__ __launch_bounds__(256, 2) void attn_kernel(const short* __restrict__ q,
                                                      const short* __restrict__ k,
                                                      const short* __restrict__ vt,
                                                      short* __restrict__ xo) {
    const int w = threadIdx.x >> 6, lane = threadIdx.x & 63;
    const int col = lane & 15, quad = lane >> 4;
    const int head = blockIdx.x & 15;
    const int cg = blockIdx.x >> 4;                  // 0..31, longest first
    const int qbase = (31 - cg) * 64 + w * 16;
    const int ntiles = 32 - cg;
    __shared__ short Ps[4 * 16 * PLD];
    short* Pw = Ps + w * 16 * PLD;
    const short* kh = k + (long long)head * TOKENS * HEADDIM;
    const short* vh = vt + (long long)head * HEADDIM * TOKENS;
    // Q fragments (A-layout): row = col, k = quad*8 (+32)
    bf8 qf[2];
    #pragma unroll
    for (int ks = 0; ks < 2; ++ks)
        qf[ks] = *(const bf8*)(q + ((long long)head * TOKENS + qbase + col) * HEADDIM + ks * 32 + quad * 8);
    f32x4 o_[4];
    float l_[4];
    #pragma unroll
    for (int n = 0; n < 4; ++n) { f32x4 z = {0.f, 0.f, 0.f, 0.f}; o_[n] = z; }
    #pragma unroll
    for (int r = 0; r < 4; ++r) l_[r] = 0.f;
    // preload K fragments for tile 0
    bf8 kfc[2][4];
    #pragma unroll
    for (int ks = 0; ks < 2; ++ks)
        #pragma unroll
        for (int nt = 0; nt < 4; ++nt)
            kfc[ks][nt] = *(const bf8*)(kh + (long long)(nt * 16 + col) * HEADDIM + ks * 32 + quad * 8);
    for (int kt = 0; kt < ntiles; ++kt) {
        const int j0 = kt * 64;
        // issue V loads for this tile + K loads for the next (latency hides
        // under QK+softmax; per-wave, no barriers anywhere)
        bf8 vfc[2][4];
        #pragma unroll
        for (int ks = 0; ks < 2; ++ks)
            #pragma unroll
            for (int nt = 0; nt < 4; ++nt)
                vfc[ks][nt] = *(const bf8*)(vh + (long long)(nt * 16 + col) * TOKENS + j0 + ks * 32 + quad * 8);
        bf8 kfn[2][4];
        if (kt + 1 < ntiles) {
            #pragma unroll
            for (int ks = 0; ks < 2; ++ks)
                #pragma unroll
                for (int nt = 0; nt < 4; ++nt)
                    kfn[ks][nt] = *(const bf8*)(kh + (long long)(j0 + 64 + nt * 16 + col) * HEADDIM + ks * 32 + quad * 8);
        }
        // S = Q K^T  [16 q][64 keys]
        f32x4 sacc[4];
        #pragma unroll
        for (int n = 0; n < 4; ++n) { f32x4 z = {0.f, 0.f, 0.f, 0.f}; sacc[n] = z; }
        #pragma unroll
        for (int ks = 0; ks < 2; ++ks)
            #pragma unroll
            for (int nt = 0; nt < 4; ++nt)
                sacc[nt] = __builtin_amdgcn_mfma_f32_16x16x32_bf16(qf[ks], kfc[ks][nt], sacc[nt], 0, 0, 0);
        // p = exp(s/8); |s/8| <= ~0.13 (unit q,k) so no max-shift needed.
        const bool diag = (j0 + 64 > qbase);
        #pragma unroll
        for (int nt = 0; nt < 4; ++nt)
            #pragma unroll
            for (int r = 0; r < 4; ++r) {
                float p = __expf(sacc[nt][r] * 0.125f);
                if (diag && (j0 + nt * 16 + col > qbase + quad * 4 + r)) p = 0.f;
                l_[r] += p;
                Pw[(quad * 4 + r) * PLD + nt * 16 + col] = f2bf(p);
            }
        // O += P V
        #pragma unroll
        for (int ks = 0; ks < 2; ++ks) {
            bf8 pf = *(const bf8*)(Pw + col * PLD + ks * 32 + quad * 8);
            #pragma unroll
            for (int nt = 0; nt < 4; ++nt)
                o_[nt] = __builtin_amdgcn_mfma_f32_16x16x32_bf16(pf, vfc[ks][nt], o_[nt], 0, 0, 0);
        }
        #pragma unroll
        for (int ks = 0; ks < 2; ++ks)
            #pragma unroll
            for (int nt = 0; nt < 4; ++nt)
                kfc[ks][nt] = kfn[ks][nt];
    }
    // epilogue: single 16-lane reduction of l per row, then normalize+store
    #pragma unroll
    for (int r = 0; r < 4; ++r) {
        float l = l_[r];
        #pragma unroll
        for (int off = 1; off < 16; off <<= 1) l += __shfl_xor(l, off);
        float inv = 1.0f / l;
        int row = qbase + quad * 4 + r;
        #pragma unroll
        for (int nt = 0; nt < 4; ++nt)
            xo[(long long)row * DIM + head * HEADDIM + nt * 16 + col] = f2bf(o_[nt][r] * inv);
    }
}

// ---------------- Router (bf16 x input) ----------------
__global__ __launch_bounds__(256) void router_kernel(const short* __restrict__ xf,
                                                     const float* __restrict__ keys_w,
                                                     const int* __restrict__ idx,
                                                     const float* __restrict__ vals,
                                                     float* __restrict__ w_route) {
    int t = blockIdx.x;
    int tid = threadIdx.x;
    int e = tid & 31, c = tid >> 5;
    const short* xr = xf + (long long)t * DIM;
    float p = 0.f;
    for (int j = 0; j < 128; ++j)
        p += bf2f(xr[c * 128 + j]) * keys_w[(c * 128 + j) * NEXP + e];
    __shared__ float part[8][32];
    part[c][e] = p;
    __syncthreads();
    if (tid < NEXP) {
        float lg = 0.f;
        #pragma unroll
        for (int cc = 0; cc < 8; ++cc) lg += part[cc][tid];
        part[0][tid] = lg;
    }
    __syncthreads();
    __shared__ float gate_s[TOPK];
    __shared__ int idx_s[TOPK];
    if (tid < TOPK) {
        int ii = idx[t * TOPK + tid];
        float g = vals[t * TOPK + tid] + part[0][ii];
        gate_s[tid] = (1.0f / (1.0f + __expf(-g))) * RSF_;
        idx_s[tid] = ii;
    }
    __syncthreads();
    if (tid < NEXP) {
        float wr = 0.f;
        #pragma unroll
        for (int kk = 0; kk < TOPK; ++kk)
            if (idx_s[kk] == tid) wr += gate_s[kk];
        w_route[(long long)t * NEXP + tid] = wr;
    }
}

// ---------------- h = silu(g) * u * w_route -> bf16 (gu bf16 [t][e*256 + {g:0-127,u:128-255}]) --
__global__ void moe_act_kernel(const short* __restrict__ gu, const float* __restrict__ w_route,
                               short* __restrict__ hb) {
    long long i = (long long)blockIdx.x * 256 + threadIdx.x;  // 8M = T*NEXP*EDIM
    int t = (int)(i >> 12);
    int e = (int)(i >> 7) & 31;
    int j = (int)(i & 127);
    float gv = bf2f(gu[(long long)t * (NEXP * 256) + e * 256 + j]);
    float uv = bf2f(gu[(long long)t * (NEXP * 256) + e * 256 + 128 + j]);
    float w = w_route[t * NEXP + e];
    float si = gv / (1.0f + __expf(-gv));
    hb[i] = f2bf(si * uv * w);
}

// ---------------- Shared-expert SwiGLU (bf16 in) -> bf16 ----------------
__global__ void swiglu_kernel(const short* __restrict__ up, short* __restrict__ hs) {
    long long i = (long long)blockIdx.x * 256 + threadIdx.x;  // 4M
    int t = (int)(i >> 11), j = (int)(i & 2047);
    float x1 = bf2f(up[(long long)t * (2 * DSHARED) + j]);
    float x2 = bf2f(up[(long long)t * (2 * DSHARED) + DSHARED + j]);
    hs[i] = f2bf(x1 / (1.0f + __expf(-x1)) * x2);
}

// ---------------- Final: out = y_moe + x_ffn_input ----------------
__global__ void final_add(const float* __restrict__ a, const float* __restrict__ b,
                          float* __restrict__ out) {
    long long i = (long long)blockIdx.x * 256 + threadIdx.x;  // 2M
    out[i] = a[i] + b[i];
}

extern "C" void kernel_launch(void* const* d_in, const int* in_sizes, int n_in,
                              void* d_out, int out_size, void* d_ws, size_t ws_size,
                              hipStream_t stream) {
    (void)in_sizes; (void)n_in; (void)out_size; (void)ws_size;
    const float* x_input     = (const float*)d_in[0];
    const int*   indices     = (const int*)d_in[1];
    const float* values      = (const float*)d_in[2];
    const float* w_attn      = (const float*)d_in[3];
    const float* w_attn_o    = (const float*)d_in[4];
    const float* attn_norm_w = (const float*)d_in[5];
    const float* ffn_norm_w  = (const float*)d_in[6];
    const float* ffn_experts = (const float*)d_in[7];
    const float* keys_w      = (const float*)d_in[8];
    const float* w_up        = (const float*)d_in[9];
    const float* w_down      = (const float*)d_in[10];
    float* out = (float*)d_out;
    float* ws  = (float*)d_ws;

    const long long M1 = 1024 * 1024;
    // Workspace (float units, lifetime-aliased; max extent 24M floats = 96MB):
    float* xffn    = ws + 0 * M1;                     // [0,2)   x_input + attn_o (atomic)
    float* ymoe    = ws + 2 * M1;                     // [2,4)   atomic accumulator
    short* xa_bf   = (short*)(ws + 4 * M1);           // [4,4.5)
    short* xf_bf   = (short*)(ws + 4 * M1 + M1 / 2);  // [4.5,5)
    short* xattn_bf= (short*)(ws + 5 * M1);           // [5,5.5)
    float* w_route = ws + 5 * M1 + M1 / 2;            // [5.5,5.6)
    float* qkv     = ws + 6 * M1;                     // [6,12)   phase A
    short* qh_bf   = (short*)(ws + 12 * M1);          // [12,12.5)
    short* kh_bf   = (short*)(ws + 12 * M1 + M1 / 2); // [12.5,13)
    short* vt_bf   = (short*)(ws + 13 * M1);          // [13,13.5)
    short* wattn_t = (short*)(ws + 14 * M1);          // [14,15.5)
    short* wattno_t= (short*)(ws + 15 * M1 + M1 / 2); // [15.5,16)
    short* wgu     = (short*)(ws + 6 * M1);           // [6,10)   phase B (qkv dead)
    short* gu_bf   = (short*)(ws + 10 * M1);          // [10,18)
    short* h_bf    = (short*)(ws + 18 * M1);          // [18,22)
    short* w2t     = (short*)(ws + 22 * M1);          // [22,24)
    short* wupt    = (short*)(ws + 6 * M1);           // [6,8)    phase C (wgu dead)
    short* up_bf   = (short*)(ws + 10 * M1);          // [10,14)  (gu_bf dead)
    short* hs_bf   = (short*)(ws + 14 * M1);          // [14,16)
    short* wdownt  = (short*)(ws + 16 * M1);          // [16,17)

    const long long EXP_STRIDE = (long long)NEXP * DIM * EDIM;  // 4M

    // ---- phase A: attention ----
    tconv<<<dim3(3072 / 32, DIM / 32, 1), 256, 0, stream>>>(w_attn, 0, wattn_t, 0, DIM, 3 * DIM);
    rmsnorm_kernel<<<TOKENS, 256, 0, stream>>>(x_input, attn_norm_w, xa_bf);
    gemm_bf16<0><<<dim3(3072 / 128, TOKENS / 128, 1), 256, 0, stream>>>(
        xa_bf, DIM, 0, wattn_t, DIM, 0, qkv, 3 * DIM, 0, TOKENS, 3 * DIM, DIM);
    qkv_post<<<(TOKENS * NHEADS) / 4, 256, 0, stream>>>(qkv, qh_bf, kh_bf);
    vtrans<<<dim3(TOKENS / 32, HEADDIM / 32, NHEADS), 256, 0, stream>>>(qkv, vt_bf);
    attn_kernel<<<512, 256, 0, stream>>>(qh_bf, kh_bf, vt_bf, xattn_bf);
    tconv<<<dim3(DIM / 32, DIM / 32, 1), 256, 0, stream>>>(w_attn_o, 0, wattno_t, 0, DIM, DIM);
    copy_f32<<<(TOKENS * DIM) / 1024, 256, 0, stream>>>(xffn, x_input);   // residual pre-init
    gemm_bf16<1><<<dim3(DIM / 128, TOKENS / 128, 4), 256, 0, stream>>>(
        xattn_bf, DIM, 0, wattno_t, DIM, 0, xffn, DIM, 0, TOKENS, DIM, DIM);

    // ---- phase B: router + experts ----
    rmsnorm_kernel<<<TOKENS, 256, 0, stream>>>(xffn, ffn_norm_w, xf_bf);
    router_kernel<<<TOKENS, 256, 0, stream>>>(xf_bf, keys_w, indices, values, w_route);
    // Wgu[e] = [256][1024]: rows 0-127 = W0[e]^T, 128-255 = W1[e]^T
    tconv<<<dim3(EDIM / 32, DIM / 32, NEXP), 256, 0, stream>>>(
        ffn_experts, (long long)DIM * EDIM, wgu, 256 * 1024, DIM, EDIM);
    tconv<<<dim3(EDIM / 32, DIM / 32, NEXP), 256, 0, stream>>>(
        ffn_experts + EXP_STRIDE, (long long)DIM * EDIM, wgu + 128 * 1024, 256 * 1024, DIM, EDIM);
    gemm_bf16<2><<<dim3(2, TOKENS / 128, NEXP), 256, 0, stream>>>(
        xf_bf, DIM, 0, wgu, DIM, 256 * 1024, gu_bf, NEXP * 256, 256, TOKENS, 256, DIM);
    moe_act_kernel<<<(TOKENS * NEXP * EDIM) / 256, 256, 0, stream>>>(gu_bf, w_route, h_bf);
    w2conv<<<(NEXP * DIM * EDIM) / 256, 256, 0, stream>>>(ffn_experts + 2 * EXP_STRIDE, w2t);
    zero_f32<<<(TOKENS * DIM) / 1024, 256, 0, stream>>>(ymoe);
    gemm_bf16<1><<<dim3(DIM / 128, TOKENS / 128, 4), 256, 0, stream>>>(
        h_bf, NEXP * EDIM, 0, w2t, NEXP * EDIM, 0, ymoe, DIM, 0, TOKENS, DIM, NEXP * EDIM);

    // ---- phase C: shared expert ----
    tconv<<<dim3((2 * DSHARED) / 32, DIM / 32, 1), 256, 0, stream>>>(w_up, 0, wupt, 0, DIM, 2 * DSHARED);
    gemm_bf16<2><<<dim3((2 * DSHARED) / 128, TOKENS / 128, 1), 256, 0, stream>>>(
        xf_bf, DIM, 0, wupt, DIM, 0, up_bf, 2 * DSHARED, 0, TOKENS, 2 * DSHARED, DIM);
    swiglu_kernel<<<(TOKENS * DSHARED) / 256, 256, 0, stream>>>(up_bf, hs_bf);
    tconv<<<dim3(DIM / 32, DSHARED / 32, 1), 256, 0, stream>>>(w_down, 0, wdownt, 0, DSHARED, DIM);
    gemm_bf16<1><<<dim3(DIM / 128, TOKENS / 128, 4), 256, 0, stream>>>(
        hs_bf, DSHARED, 0, wdownt, DSHARED, 0, ymoe, DIM, 0, TOKENS, DIM, DSHARED);

    // ---- final residual ----
    final_add<<<(TOKENS * DIM) / 256, 256, 0, stream>>>(ymoe, xffn, out);
}

// Round 7
// 538.943 us; speedup vs baseline: 1.0059x; 1.0059x over previous
//
#include <hip/hip_runtime.h>
#include <math.h>

#define TOKENS 2048
#define DIM 1024
#define NHEADS 16
#define HEADDIM 64
#define NEXP 32
#define EDIM 128
#define TOPK 8
#define DSHARED 2048
#define RSF_ 2.5f
#define EPS_ 1e-6f

using bf8  = __attribute__((ext_vector_type(8))) short;   // 8 bf16 in 4 VGPRs
using f32x4 = __attribute__((ext_vector_type(4))) float;  // MFMA accumulator

__device__ __forceinline__ short f2bf(float f) {
    unsigned u = __float_as_uint(f);
    unsigned r = (u + 0x7fffu + ((u >> 16) & 1u)) >> 16;
    return (short)r;
}
__device__ __forceinline__ float bf2f(short s) {
    return __uint_as_float(((unsigned)(unsigned short)s) << 16);
}

// Direct global->LDS DMA, 16B per lane. LDS dest = wave-uniform base + lane*16.
__device__ __forceinline__ void async16(const short* g, const short* l) {
    __builtin_amdgcn_global_load_lds(
        (const __attribute__((address_space(1))) void*)(unsigned long long)g,
        (__attribute__((address_space(3))) void*)(unsigned)(unsigned long long)l,
        16, 0, 0);
}

// ---------------- RMSNorm: one block per token, bf16 output ----------------
__global__ __launch_bounds__(256) void rmsnorm_kernel(const float* __restrict__ x,
                                                      const float* __restrict__ w,
                                                      short* __restrict__ out) {
    int row = blockIdx.x;
    const float* xr = x + (long long)row * DIM;
    int t = threadIdx.x;
    float4 xv = ((const float4*)xr)[t];
    float ss = xv.x*xv.x + xv.y*xv.y + xv.z*xv.z + xv.w*xv.w;
    #pragma unroll
    for (int off = 32; off; off >>= 1) ss += __shfl_down(ss, off);
    __shared__ float warps[4];
    if ((t & 63) == 0) warps[t >> 6] = ss;
    __syncthreads();
    float tot = warps[0] + warps[1] + warps[2] + warps[3];
    float scale = rsqrtf(tot / (float)DIM + EPS_);
    float4 wv = ((const float4*)w)[t];
    short4 o;
    o.x = f2bf(xv.x * scale * wv.x);
    o.y = f2bf(xv.y * scale * wv.y);
    o.z = f2bf(xv.z * scale * wv.z);
    o.w = f2bf(xv.w * scale * wv.w);
    ((short4*)(out + (long long)row * DIM))[t] = o;
}

// ---------------- Transpose + convert: fp32 in[K][N] -> bf16 out[N][K] ----------------
__global__ __launch_bounds__(256) void tconv(const float* __restrict__ in, long long sin,
                                             short* __restrict__ out, long long sout,
                                             int K, int N) {
    in  += (long long)blockIdx.z * sin;
    out += (long long)blockIdx.z * sout;
    __shared__ float t[32][33];
    int n0 = blockIdx.x * 32, k0 = blockIdx.y * 32;
    int tx = threadIdx.x & 31, ty = threadIdx.x >> 5;  // ty 0..7
    #pragma unroll
    for (int r = ty; r < 32; r += 8)
        t[r][tx] = in[(long long)(k0 + r) * N + n0 + tx];
    __syncthreads();
    #pragma unroll
    for (int r = ty; r < 32; r += 8)
        out[(long long)(n0 + r) * K + k0 + tx] = f2bf(t[tx][r]);
}

// W2 [e][d][h] fp32 -> bf16 [d][(e*128+h)]
__global__ void w2conv(const float* __restrict__ in, short* __restrict__ out) {
    long long i = (long long)blockIdx.x * 256 + threadIdx.x;  // 4M
    int e = (int)(i >> 17);
    int d = (int)(i >> 7) & 1023;
    int h = (int)(i & 127);
    out[(long long)d * (NEXP * EDIM) + e * EDIM + h] = f2bf(in[i]);
}

// ---------------- bf16 MFMA GEMM: C[M][N] = A[M][K] @ Bt[N][K]^T ----------------
// 128x128 tile, BK=64, XOR-swizzled LDS (conflict-free ds_read_b128),
// async global->LDS staging.
// MODE 0: f32 store, z = batch.  MODE 1: f32 atomicAdd, z = K-split index.
// MODE 2: bf16 store, z = batch.
template<int MODE>
__global__ __launch_bounds__(256) void gemm_bf16(const short* __restrict__ A, int lda, long long sA,
                                                 const short* __restrict__ Bt, int ldb, long long sBt,
                                                 void* __restrict__ Cv, int ldc, long long sC,
                                                 int M, int N, int K) {
    int koff = 0, Ksub = K;
    if (MODE == 1) {
        Ksub = K / gridDim.z;
        koff = blockIdx.z * Ksub;
    } else {
        A  += (long long)blockIdx.z * sA;
        Bt += (long long)blockIdx.z * sBt;
    }
    float* Cf = (float*)Cv;
    short* Cs = (short*)Cv;
    if (MODE != 1) { Cf += (long long)blockIdx.z * sC; Cs += (long long)blockIdx.z * sC; }
    const int m0 = blockIdx.y * 128, n0 = blockIdx.x * 128;
    __shared__ short As[128 * 64];
    __shared__ short Bs[128 * 64];
    const int tid = threadIdx.x, lane = tid & 63, w = tid >> 6;
    const int wm = (w >> 1) * 64, wn = (w & 1) * 64;
    // DMA: wave w stages rows [w*32, w*32+32). Instr c covers rows c*8+drow.
    // Source col XOR-swizzled so LDS(r, j16) holds global chunk j16^(r&7).
    const int drow = lane >> 3;                  // 0..7
    const int dcol = ((lane & 7) ^ drow) * 8;    // swizzled 16B-chunk col, shorts
    const short* ag = A + (long long)(m0 + w * 32 + drow) * lda + koff + dcol;
    const short* bg = Bt + (long long)(n0 + w * 32 + drow) * ldb + koff + dcol;
    const short* lA = As + w * 32 * 64;
    const short* lB = Bs + w * 32 * 64;
    f32x4 acc[4][4];
    #pragma unroll
    for (int i = 0; i < 4; ++i)
        #pragma unroll
        for (int j = 0; j < 4; ++j) { f32x4 z = {0.f, 0.f, 0.f, 0.f}; acc[i][j] = z; }
    const int ra = lane & 15, quad = lane >> 4;
    // fragment chunk (h*4+quad) lives at swizzled col (h*4+quad)^(ra&7)
    const int fs0 = ((quad + 0) ^ (ra & 7)) * 8;
    const int fs1 = ((quad + 4) ^ (ra & 7)) * 8;
    for (int k0 = 0; k0 < Ksub; k0 += 64) {
        #pragma unroll
        for (int c = 0; c < 4; ++c) {
            async16(ag + (long long)(c * 8) * lda + k0, lA + c * 512);
            async16(bg + (long long)(c * 8) * ldb + k0, lB + c * 512);
        }
        __syncthreads();   // drains vmcnt -> tiles resident
        #pragma unroll
        for (int h = 0; h < 2; ++h) {
            const int fs = h ? fs1 : fs0;
            bf8 af[4], bfv[4];
            #pragma unroll
            for (int i = 0; i < 4; ++i) af[i]  = *(const bf8*)(As + (wm + i * 16 + ra) * 64 + fs);
            #pragma unroll
            for (int j = 0; j < 4; ++j) bfv[j] = *(const bf8*)(Bs + (wn + j * 16 + ra) * 64 + fs);
            #pragma unroll
            for (int i = 0; i < 4; ++i)
                #pragma unroll
                for (int j = 0; j < 4; ++j)
                    acc[i][j] = __builtin_amdgcn_mfma_f32_16x16x32_bf16(af[i], bfv[j], acc[i][j], 0, 0, 0);
        }
        __syncthreads();   // reads done before next DMA overwrites
    }
    const int cr = quad * 4, cc = ra;
    #pragma unroll
    for (int i = 0; i < 4; ++i) {
        #pragma unroll
        for (int r = 0; r < 4; ++r) {
            int row = m0 + wm + i * 16 + cr + r;
            long long base = (long long)row * ldc + n0 + wn + cc;
            #pragma unroll
            for (int j = 0; j < 4; ++j) {
                float v = acc[i][j][r];
                if (MODE == 0) Cf[base + j * 16] = v;
                if (MODE == 1) atomicAdd(Cf + base + j * 16, v);
                if (MODE == 2) Cs[base + j * 16] = f2bf(v);
            }
        }
    }
}

// ---------------- zero / copy helpers (float4-vectorized) ----------------
__global__ void zero_f32(float* __restrict__ p) {
    long long i = (long long)blockIdx.x * 256 + threadIdx.x;
    ((float4*)p)[i] = make_float4(0.f, 0.f, 0.f, 0.f);
}
__global__ void copy_f32(float* __restrict__ dst, const float* __restrict__ src) {
    long long i = (long long)blockIdx.x * 256 + threadIdx.x;
    ((float4*)dst)[i] = ((const float4*)src)[i];
}

// ---------------- QKV post: split heads, l2norm(q,k), RoPE -> bf16 [h][s][64] ----------------
__global__ __launch_bounds__(256) void qkv_post(const float* __restrict__ qkv,
                                                short* __restrict__ q,
                                                short* __restrict__ k) {
    int lane = threadIdx.x & 63;
    int sh = blockIdx.x * 4 + (threadIdx.x >> 6);
    int s = sh >> 4;
    int h = sh & 15;
    const float* base = qkv + (long long)s * 3 * DIM;
    float qv = base[h * HEADDIM + lane];
    float kv = base[DIM + h * HEADDIM + lane];
    float qs = qv * qv, ks = kv * kv;
    #pragma unroll
    for (int off = 32; off; off >>= 1) {
        qs += __shfl_xor(qs, off);
        ks += __shfl_xor(ks, off);
    }
    qv /= fmaxf(sqrtf(qs), EPS_);
    kv /= fmaxf(sqrtf(ks), EPS_);
    int i = lane & 31;
    float f = (float)s * powf(10000.0f, -(float)i / 32.0f);
    float c = cosf(f), sn = sinf(f);
    float qo = __shfl_xor(qv, 32);
    float ko = __shfl_xor(kv, 32);
    float sgn = (lane < 32) ? sn : -sn;
    float qr = qv * c + qo * sgn;
    float kr = kv * c + ko * sgn;
    long long o = ((long long)h * TOKENS + s) * HEADDIM + lane;
    q[o] = f2bf(qr);
    k[o] = f2bf(kr);
}

// ---------------- V transpose: qkv fp32 [s][3D] -> vt bf16 [h][64][2048] ----------------
__global__ __launch_bounds__(256) void vtrans(const float* __restrict__ qkv,
                                              short* __restrict__ vt) {
    int h = blockIdx.z;
    int s0 = blockIdx.x * 32, d0 = blockIdx.y * 32;
    __shared__ float t[32][33];
    int tx = threadIdx.x & 31, ty = threadIdx.x >> 5;
    #pragma unroll
    for (int r = ty; r < 32; r += 8)
        t[r][tx] = qkv[(long long)(s0 + r) * (3 * DIM) + 2 * DIM + h * HEADDIM + d0 + tx];
    __syncthreads();
    #pragma unroll
    for (int r = ty; r < 32; r += 8)
        vt[((long long)h * HEADDIM + d0 + r) * TOKENS + s0 + tx] = f2bf(t[tx][r]);
}

// ---------------- MFMA flash attention, key-split with linear combine ----------------
// The no-max softmax (safe: qk-norm bounds |s/8|<=~0.13) makes O-partial and
// l-partial plain sums over keys -> split the causal triangle into uniform
// chunks of <=8 key-tiles (16 heads x 80 chunks = 1280 blocks) and combine
// partials with fp32 atomicAdd. One wave = 16 q-rows; K/V B-fragments loaded
// straight from global; no barriers; P via wave-private LDS (stride 68).
#define PLD 68
__global__ __launch_bounds__(256, 2) void attn_kernel(const short* __restrict__ q,
                                                      const short* __restrict__ k,
                                                      const short* __restrict__ vt,
                                                      float* __restrict__ Oacc,
                                                      float* __restrict__ lacc) {
    const int w = threadIdx.x >> 6, lane = threadIdx.x & 63;
    const int col = lane & 15, quad = lane >> 4;
    const int head = blockIdx.x / 80;
    const int t = blockIdx.x % 80;
    int qb, ch;
    if (t < 8)       { qb = t;                ch = 0; }
    else if (t < 24) { qb = 8 + (t - 8) / 2;  ch = (t - 8) % 2; }
    else if (t < 48) { qb = 16 + (t - 24) / 3; ch = (t - 24) % 3; }
    else             { qb = 24 + (t - 48) / 4; ch = (t - 48) % 4; }
    const int nch = qb / 8 + 1;
    const int ntk = qb + 1;                       // causal key-tiles for this q-block
    const int per = (ntk + nch - 1) / nch;
    const int t0 = ch * per;
    const int t1 = (t0 + per < ntk) ? t0 + per : ntk;
    const int qbase = qb * 64 + w * 16;
    __shared__ short Ps[4 * 16 * PLD];
    short* Pw = Ps + w * 16 * PLD;
    const short* kh = k + (long long)head * TOKENS * HEADDIM;
    const short* vh = vt + (long long)head * HEADDIM * TOKENS;
    // Q fragments (A-layout): row = col, k = quad*8 (+32)
    bf8 qf[2];
    #pragma unroll
    for (int ks = 0; ks < 2; ++ks)
        qf[ks] = *(const bf8*)(q + ((long long)head * TOKENS + qbase + col) * HEADDIM + ks * 32 + quad * 8);
    f32x4 o_[4];
    float l_[4];
    #pragma unroll
    for (int n = 0; n < 4; ++n) { f32x4 z = {0.f, 0.f, 0.f, 0.f}; o_[n] = z; }
    #pragma unroll
    for (int r = 0; r < 4; ++r) l_[r] = 0.f;
    // preload K fragments for tile t0
    bf8 kfc[2][4];
    #pragma unroll
    for (int ks = 0; ks < 2; ++ks)
        #pragma unroll
        for (int nt = 0; nt < 4; ++nt)
            kfc[ks][nt] = *(const bf8*)(kh + (long long)(t0 * 64 + nt * 16 + col) * HEADDIM + ks * 32 + quad * 8);
    for (int kt = t0; kt < t1; ++kt) {
        const int j0 = kt * 64;
        // V loads for this tile + K loads for the next (latency hides under QK+softmax)
        bf8 vfc[2][4];
        #pragma unroll
        for (int ks = 0; ks < 2; ++ks)
            #pragma unroll
            for (int nt = 0; nt < 4; ++nt)
                vfc[ks][nt] = *(const bf8*)(vh + (long long)(nt * 16 + col) * TOKENS + j0 + ks * 32 + quad * 8);
        bf8 kfn[2][4];
        if (kt + 1 < t1) {
            #pragma unroll
            for (int ks = 0; ks < 2; ++ks)
                #pragma unroll
                for (int nt = 0; nt < 4; ++nt)
                    kfn[ks][nt] = *(const bf8*)(kh + (long long)(j0 + 64 + nt * 16 + col) * HEADDIM + ks * 32 + quad * 8);
        }
        // S = Q K^T  [16 q][64 keys]
        f32x4 sacc[4];
        #pragma unroll
        for (int n = 0; n < 4; ++n) { f32x4 z = {0.f, 0.f, 0.f, 0.f}; sacc[n] = z; }
        #pragma unroll
        for (int ks = 0; ks < 2; ++ks)
            #pragma unroll
            for (int nt = 0; nt < 4; ++nt)
                sacc[nt] = __builtin_amdgcn_mfma_f32_16x16x32_bf16(qf[ks], kfc[ks][nt], sacc[nt], 0, 0, 0);
        // p = exp(s/8); |s/8| <= ~0.13 (unit q,k) so no max-shift needed.
        const bool diag = (j0 + 64 > qbase);
        #pragma unroll
        for (int nt = 0; nt < 4; ++nt)
            #pragma unroll
            for (int r = 0; r < 4; ++r) {
                float p = __expf(sacc[nt][r] * 0.125f);
                if (diag && (j0 + nt * 16 + col > qbase + quad * 4 + r)) p = 0.f;
                l_[r] += p;
                Pw[(quad * 4 + r) * PLD + nt * 16 + col] = f2bf(p);
            }
        // O += P V
        #pragma unroll
        for (int ks = 0; ks < 2; ++ks) {
            bf8 pf = *(const bf8*)(Pw + col * PLD + ks * 32 + quad * 8);
            #pragma unroll
            for (int nt = 0; nt < 4; ++nt)
                o_[nt] = __builtin_amdgcn_mfma_f32_16x16x32_bf16(pf, vfc[ks][nt], o_[nt], 0, 0, 0);
        }
        #pragma unroll
        for (int ks = 0; ks < 2; ++ks)
            #pragma unroll
            for (int nt = 0; nt < 4; ++nt)
                kfc[ks][nt] = kfn[ks][nt];
    }
    // epilogue: combine partials (linear in keys -> exact)
    #pragma unroll
    for (int r = 0; r < 4; ++r) {
        int row = qbase + quad * 4 + r;
        #pragma unroll
        for (int nt = 0; nt < 4; ++nt)
            atomicAdd(Oacc + (long long)row * DIM + head * HEADDIM + nt * 16 + col, o_[nt][r]);
        float l = l_[r];
        #pragma unroll
        for (int off = 1; off < 16; off <<= 1) l += __shfl_xor(l, off);
        if (col == 0) atomicAdd(lacc + row * NHEADS + head, l);
    }
}

// ---------------- Attention normalize: xo = Oacc / l -> bf16 ----------------
__global__ void attn_norm(const float* __restrict__ Oacc, const float* __restrict__ lacc,
                          short* __restrict__ xo) {
    long long i = (long long)blockIdx.x * 256 + threadIdx.x;  // 2M
    int row = (int)(i >> 10), col = (int)(i & 1023);
    xo[i] = f2bf(Oacc[i] / lacc[row * NHEADS + (col >> 6)]);
}

// ---------------- Router (bf16 x input) ----------------
__global__ __launch_bounds__(256) void router_kernel(const short* __restrict__ xf,
                                                     const float* __restrict__ keys_w,
                                                     const int* __restrict__ idx,
                                                     const float* __restrict__ vals,
                                                     float* __restrict__ w_route) {
    int t = blockIdx.x;
    int tid = threadIdx.x;
    int e = tid & 31, c = tid >> 5;
    const short* xr = xf + (long long)t * DIM;
    float p = 0.f;
    for (int j = 0; j < 128; ++j)
        p += bf2f(xr[c * 128 + j]) * keys_w[(c * 128 + j) * NEXP + e];
    __shared__ float part[8][32];
    part[c][e] = p;
    __syncthreads();
    if (tid < NEXP) {
        float lg = 0.f;
        #pragma unroll
        for (int cc = 0; cc < 8; ++cc) lg += part[cc][tid];
        part[0][tid] = lg;
    }
    __syncthreads();
    __shared__ float gate_s[TOPK];
    __shared__ int idx_s[TOPK];
    if (tid < TOPK) {
        int ii = idx[t * TOPK + tid];
        float g = vals[t * TOPK + tid] + part[0][ii];
        gate_s[tid] = (1.0f / (1.0f + __expf(-g))) * RSF_;
        idx_s[tid] = ii;
    }
    __syncthreads();
    if (tid < NEXP) {
        float wr = 0.f;
        #pragma unroll
        for (int kk = 0; kk < TOPK; ++kk)
            if (idx_s[kk] == tid) wr += gate_s[kk];
        w_route[(long long)t * NEXP + tid] = wr;
    }
}

// ---------------- h = silu(g) * u * w_route -> bf16 (gu bf16 [t][e*256 + {g:0-127,u:128-255}]) --
__global__ void moe_act_kernel(const short* __restrict__ gu, const float* __restrict__ w_route,
                               short* __restrict__ hb) {
    long long i = (long long)blockIdx.x * 256 + threadIdx.x;  // 8M = T*NEXP*EDIM
    int t = (int)(i >> 12);
    int e = (int)(i >> 7) & 31;
    int j = (int)(i & 127);
    float gv = bf2f(gu[(long long)t * (NEXP * 256) + e * 256 + j]);
    float uv = bf2f(gu[(long long)t * (NEXP * 256) + e * 256 + 128 + j]);
    float w = w_route[t * NEXP + e];
    float si = gv / (1.0f + __expf(-gv));
    hb[i] = f2bf(si * uv * w);
}

// ---------------- Shared-expert SwiGLU (bf16 in) -> bf16 ----------------
__global__ void swiglu_kernel(const short* __restrict__ up, short* __restrict__ hs) {
    long long i = (long long)blockIdx.x * 256 + threadIdx.x;  // 4M
    int t = (int)(i >> 11), j = (int)(i & 2047);
    float x1 = bf2f(up[(long long)t * (2 * DSHARED) + j]);
    float x2 = bf2f(up[(long long)t * (2 * DSHARED) + DSHARED + j]);
    hs[i] = f2bf(x1 / (1.0f + __expf(-x1)) * x2);
}

// ---------------- Final: out = y_moe + x_ffn_input ----------------
__global__ void final_add(const float* __restrict__ a, const float* __restrict__ b,
                          float* __restrict__ out) {
    long long i = (long long)blockIdx.x * 256 + threadIdx.x;  // 2M
    out[i] = a[i] + b[i];
}

extern "C" void kernel_launch(void* const* d_in, const int* in_sizes, int n_in,
                              void* d_out, int out_size, void* d_ws, size_t ws_size,
                              hipStream_t stream) {
    (void)in_sizes; (void)n_in; (void)out_size; (void)ws_size;
    const float* x_input     = (const float*)d_in[0];
    const int*   indices     = (const int*)d_in[1];
    const float* values      = (const float*)d_in[2];
    const float* w_attn      = (const float*)d_in[3];
    const float* w_attn_o    = (const float*)d_in[4];
    const float* attn_norm_w = (const float*)d_in[5];
    const float* ffn_norm_w  = (const float*)d_in[6];
    const float* ffn_experts = (const float*)d_in[7];
    const float* keys_w      = (const float*)d_in[8];
    const float* w_up        = (const float*)d_in[9];
    const float* w_down      = (const float*)d_in[10];
    float* out = (float*)d_out;
    float* ws  = (float*)d_ws;

    const long long M1 = 1024 * 1024;
    // Workspace (float units, lifetime-aliased; max extent 24M floats = 96MB):
    float* xffn    = ws + 0 * M1;                     // [0,2)   x_input + attn_o (atomic)
    float* ymoe    = ws + 2 * M1;                     // [2,4)   atomic accumulator
    short* xa_bf   = (short*)(ws + 4 * M1);           // [4,4.5)
    short* xf_bf   = (short*)(ws + 4 * M1 + M1 / 2);  // [4.5,5)
    short* xattn_bf= (short*)(ws + 5 * M1);           // [5,5.5)
    float* w_route = ws + 5 * M1 + M1 / 2;            // [5.5,5.6)
    float* qkv     = ws + 6 * M1;                     // [6,12)   phase A (dead after vtrans)
    float* Oacc    = ws + 6 * M1;                     // [6,8)    attn fp32 accum (after qkv dead)
    float* lacc    = ws + 8 * M1;                     // [8, 8+32K)
    short* qh_bf   = (short*)(ws + 12 * M1);          // [12,12.5)
    short* kh_bf   = (short*)(ws + 12 * M1 + M1 / 2); // [12.5,13)
    short* vt_bf   = (short*)(ws + 13 * M1);          // [13,13.5)
    short* wattn_t = (short*)(ws + 14 * M1);          // [14,15.5)
    short* wattno_t= (short*)(ws + 15 * M1 + M1 / 2); // [15.5,16)
    short* wgu     = (short*)(ws + 6 * M1);           // [6,10)   phase B (Oacc dead)
    short* gu_bf   = (short*)(ws + 10 * M1);          // [10,18)
    short* h_bf    = (short*)(ws + 18 * M1);          // [18,22)
    short* w2t     = (short*)(ws + 22 * M1);          // [22,24)
    short* wupt    = (short*)(ws + 6 * M1);           // [6,8)    phase C (wgu dead)
    short* up_bf   = (short*)(ws + 10 * M1);          // [10,14)  (gu_bf dead)
    short* hs_bf   = (short*)(ws + 14 * M1);          // [14,16)
    short* wdownt  = (short*)(ws + 16 * M1);          // [16,17)

    const long long EXP_STRIDE = (long long)NEXP * DIM * EDIM;  // 4M

    // ---- phase A: attention ----
    tconv<<<dim3(3072 / 32, DIM / 32, 1), 256, 0, stream>>>(w_attn, 0, wattn_t, 0, DIM, 3 * DIM);
    rmsnorm_kernel<<<TOKENS, 256, 0, stream>>>(x_input, attn_norm_w, xa_bf);
    gemm_bf16<0><<<dim3(3072 / 128, TOKENS / 128, 1), 256, 0, stream>>>(
        xa_bf, DIM, 0, wattn_t, DIM, 0, qkv, 3 * DIM, 0, TOKENS, 3 * DIM, DIM);
    qkv_post<<<(TOKENS * NHEADS) / 4, 256, 0, stream>>>(qkv, qh_bf, kh_bf);
    vtrans<<<dim3(TOKENS / 32, HEADDIM / 32, NHEADS), 256, 0, stream>>>(qkv, vt_bf);
    zero_f32<<<(2 * (int)M1 + TOKENS * NHEADS) / 1024, 256, 0, stream>>>(Oacc);  // Oacc + lacc (contiguous)
    attn_kernel<<<NHEADS * 80, 256, 0, stream>>>(qh_bf, kh_bf, vt_bf, Oacc, lacc);
    attn_norm<<<(TOKENS * DIM) / 256, 256, 0, stream>>>(Oacc, lacc, xattn_bf);
    tconv<<<dim3(DIM / 32, DIM / 32, 1), 256, 0, stream>>>(w_attn_o, 0, wattno_t, 0, DIM, DIM);
    copy_f32<<<(TOKENS * DIM) / 1024, 256, 0, stream>>>(xffn, x_input);   // residual pre-init
    gemm_bf16<1><<<dim3(DIM / 128, TOKENS / 128, 4), 256, 0, stream>>>(
        xattn_bf, DIM, 0, wattno_t, DIM, 0, xffn, DIM, 0, TOKENS, DIM, DIM);

    // ---- phase B: router + experts ----
    rmsnorm_kernel<<<TOKENS, 256, 0, stream>>>(xffn, ffn_norm_w, xf_bf);
    router_kernel<<<TOKENS, 256, 0, stream>>>(xf_bf, keys_w, indices, values, w_route);
    // Wgu[e] = [256][1024]: rows 0-127 = W0[e]^T, 128-255 = W1[e]^T
    tconv<<<dim3(EDIM / 32, DIM / 32, NEXP), 256, 0, stream>>>(
        ffn_experts, (long long)DIM * EDIM, wgu, 256 * 1024, DIM, EDIM);
    tconv<<<dim3(EDIM / 32, DIM / 32, NEXP), 256, 0, stream>>>(
        ffn_experts + EXP_STRIDE, (long long)DIM * EDIM, wgu + 128 * 1024, 256 * 1024, DIM, EDIM);
    gemm_bf16<2><<<dim3(2, TOKENS / 128, NEXP), 256, 0, stream>>>(
        xf_bf, DIM, 0, wgu, DIM, 256 * 1024, gu_bf, NEXP * 256, 256, TOKENS, 256, DIM);
    moe_act_kernel<<<(TOKENS * NEXP * EDIM) / 256, 256, 0, stream>>>(gu_bf, w_route, h_bf);
    w2conv<<<(NEXP * DIM * EDIM) / 256, 256, 0, stream>>>(ffn_experts + 2 * EXP_STRIDE, w2t);
    zero_f32<<<(TOKENS * DIM) / 1024, 256, 0, stream>>>(ymoe);
    gemm_bf16<1><<<dim3(DIM / 128, TOKENS / 128, 4), 256, 0, stream>>>(
        h_bf, NEXP * EDIM, 0, w2t, NEXP * EDIM, 0, ymoe, DIM, 0, TOKENS, DIM, NEXP * EDIM);

    // ---- phase C: shared expert ----
    tconv<<<dim3((2 * DSHARED) / 32, DIM / 32, 1), 256, 0, stream>>>(w_up, 0, wupt, 0, DIM, 2 * DSHARED);
    gemm_bf16<2><<<dim3((2 * DSHARED) / 128, TOKENS / 128, 1), 256, 0, stream>>>(
        xf_bf, DIM, 0, wupt, DIM, 0, up_bf, 2 * DSHARED, 0, TOKENS, 2 * DSHARED, DIM);
    swiglu_kernel<<<(TOKENS * DSHARED) / 256, 256, 0, stream>>>(up_bf, hs_bf);
    tconv<<<dim3(DIM / 32, DSHARED / 32, 1), 256, 0, stream>>>(w_down, 0, wdownt, 0, DSHARED, DIM);
    gemm_bf16<1><<<dim3(DIM / 128, TOKENS / 128, 4), 256, 0, stream>>>(
        hs_bf, DSHARED, 0, wdownt, DSHARED, 0, ymoe, DIM, 0, TOKENS, DIM, DSHARED);

    // ---- final residual ----
    final_add<<<(TOKENS * DIM) / 256, 256, 0, stream>>>(ymoe, xffn, out);
}

// Round 8
// 535.626 us; speedup vs baseline: 1.0121x; 1.0062x over previous
//
#include <hip/hip_runtime.h>
#include <math.h>

#define TOKENS 2048
#define DIM 1024
#define NHEADS 16
#define HEADDIM 64
#define NEXP 32
#define EDIM 128
#define TOPK 8
#define DSHARED 2048
#define RSF_ 2.5f
#define EPS_ 1e-6f

using bf8  = __attribute__((ext_vector_type(8))) short;   // 8 bf16 in 4 VGPRs
using f32x4 = __attribute__((ext_vector_type(4))) float;  // MFMA accumulator

__device__ __forceinline__ short f2bf(float f) {
    unsigned u = __float_as_uint(f);
    unsigned r = (u + 0x7fffu + ((u >> 16) & 1u)) >> 16;
    return (short)r;
}
__device__ __forceinline__ float bf2f(short s) {
    return __uint_as_float(((unsigned)(unsigned short)s) << 16);
}

// Direct global->LDS DMA, 16B per lane. LDS dest = wave-uniform base + lane*16.
__device__ __forceinline__ void async16(const short* g, const short* l) {
    __builtin_amdgcn_global_load_lds(
        (const __attribute__((address_space(1))) void*)(unsigned long long)g,
        (__attribute__((address_space(3))) void*)(unsigned)(unsigned long long)l,
        16, 0, 0);
}

// ---------------- RMSNorm: one block per token, bf16 output ----------------
__global__ __launch_bounds__(256) void rmsnorm_kernel(const float* __restrict__ x,
                                                      const float* __restrict__ w,
                                                      short* __restrict__ out) {
    int row = blockIdx.x;
    const float* xr = x + (long long)row * DIM;
    int t = threadIdx.x;
    float4 xv = ((const float4*)xr)[t];
    float ss = xv.x*xv.x + xv.y*xv.y + xv.z*xv.z + xv.w*xv.w;
    #pragma unroll
    for (int off = 32; off; off >>= 1) ss += __shfl_down(ss, off);
    __shared__ float warps[4];
    if ((t & 63) == 0) warps[t >> 6] = ss;
    __syncthreads();
    float tot = warps[0] + warps[1] + warps[2] + warps[3];
    float scale = rsqrtf(tot / (float)DIM + EPS_);
    float4 wv = ((const float4*)w)[t];
    short4 o;
    o.x = f2bf(xv.x * scale * wv.x);
    o.y = f2bf(xv.y * scale * wv.y);
    o.z = f2bf(xv.z * scale * wv.z);
    o.w = f2bf(xv.w * scale * wv.w);
    ((short4*)(out + (long long)row * DIM))[t] = o;
}

// ---------------- Transpose + convert: fp32 in[K][N] -> bf16 out[N][K] ----------------
__global__ __launch_bounds__(256) void tconv(const float* __restrict__ in, long long sin,
                                             short* __restrict__ out, long long sout,
                                             int K, int N) {
    in  += (long long)blockIdx.z * sin;
    out += (long long)blockIdx.z * sout;
    __shared__ float t[32][33];
    int n0 = blockIdx.x * 32, k0 = blockIdx.y * 32;
    int tx = threadIdx.x & 31, ty = threadIdx.x >> 5;  // ty 0..7
    #pragma unroll
    for (int r = ty; r < 32; r += 8)
        t[r][tx] = in[(long long)(k0 + r) * N + n0 + tx];
    __syncthreads();
    #pragma unroll
    for (int r = ty; r < 32; r += 8)
        out[(long long)(n0 + r) * K + k0 + tx] = f2bf(t[tx][r]);
}

// W2 [e][d][h] fp32 -> bf16 [d][(e*128+h)]
__global__ void w2conv(const float* __restrict__ in, short* __restrict__ out) {
    long long i = (long long)blockIdx.x * 256 + threadIdx.x;  // 4M
    int e = (int)(i >> 17);
    int d = (int)(i >> 7) & 1023;
    int h = (int)(i & 127);
    out[(long long)d * (NEXP * EDIM) + e * EDIM + h] = f2bf(in[i]);
}

// ---------------- bf16 MFMA GEMM: C[M][N] = A[M][K] @ Bt[N][K]^T ----------------
// 128x128 tile, BK=64, XOR-swizzled LDS (conflict-free ds_read_b128),
// async global->LDS staging.
// MODE 0: f32 store, z = batch.  MODE 1: f32 atomicAdd, z = K-split index.
// MODE 2: bf16 store, z = batch.
template<int MODE>
__global__ __launch_bounds__(256) void gemm_bf16(const short* __restrict__ A, int lda, long long sA,
                                                 const short* __restrict__ Bt, int ldb, long long sBt,
                                                 void* __restrict__ Cv, int ldc, long long sC,
                                                 int M, int N, int K) {
    int koff = 0, Ksub = K;
    if (MODE == 1) {
        Ksub = K / gridDim.z;
        koff = blockIdx.z * Ksub;
    } else {
        A  += (long long)blockIdx.z * sA;
        Bt += (long long)blockIdx.z * sBt;
    }
    float* Cf = (float*)Cv;
    short* Cs = (short*)Cv;
    if (MODE != 1) { Cf += (long long)blockIdx.z * sC; Cs += (long long)blockIdx.z * sC; }
    const int m0 = blockIdx.y * 128, n0 = blockIdx.x * 128;
    __shared__ short As[128 * 64];
    __shared__ short Bs[128 * 64];
    const int tid = threadIdx.x, lane = tid & 63, w = tid >> 6;
    const int wm = (w >> 1) * 64, wn = (w & 1) * 64;
    // DMA: wave w stages rows [w*32, w*32+32). Instr c covers rows c*8+drow.
    // Source col XOR-swizzled so LDS(r, j16) holds global chunk j16^(r&7).
    const int drow = lane >> 3;                  // 0..7
    const int dcol = ((lane & 7) ^ drow) * 8;    // swizzled 16B-chunk col, shorts
    const short* ag = A + (long long)(m0 + w * 32 + drow) * lda + koff + dcol;
    const short* bg = Bt + (long long)(n0 + w * 32 + drow) * ldb + koff + dcol;
    const short* lA = As + w * 32 * 64;
    const short* lB = Bs + w * 32 * 64;
    f32x4 acc[4][4];
    #pragma unroll
    for (int i = 0; i < 4; ++i)
        #pragma unroll
        for (int j = 0; j < 4; ++j) { f32x4 z = {0.f, 0.f, 0.f, 0.f}; acc[i][j] = z; }
    const int ra = lane & 15, quad = lane >> 4;
    // fragment chunk (h*4+quad) lives at swizzled col (h*4+quad)^(ra&7)
    const int fs0 = ((quad + 0) ^ (ra & 7)) * 8;
    const int fs1 = ((quad + 4) ^ (ra & 7)) * 8;
    for (int k0 = 0; k0 < Ksub; k0 += 64) {
        #pragma unroll
        for (int c = 0; c < 4; ++c) {
            async16(ag + (long long)(c * 8) * lda + k0, lA + c * 512);
            async16(bg + (long long)(c * 8) * ldb + k0, lB + c * 512);
        }
        __syncthreads();   // drains vmcnt -> tiles resident
        #pragma unroll
        for (int h = 0; h < 2; ++h) {
            const int fs = h ? fs1 : fs0;
            bf8 af[4], bfv[4];
            #pragma unroll
            for (int i = 0; i < 4; ++i) af[i]  = *(const bf8*)(As + (wm + i * 16 + ra) * 64 + fs);
            #pragma unroll
            for (int j = 0; j < 4; ++j) bfv[j] = *(const bf8*)(Bs + (wn + j * 16 + ra) * 64 + fs);
            #pragma unroll
            for (int i = 0; i < 4; ++i)
                #pragma unroll
                for (int j = 0; j < 4; ++j)
                    acc[i][j] = __builtin_amdgcn_mfma_f32_16x16x32_bf16(af[i], bfv[j], acc[i][j], 0, 0, 0);
        }
        __syncthreads();   // reads done before next DMA overwrites
    }
    const int cr = quad * 4, cc = ra;
    #pragma unroll
    for (int i = 0; i < 4; ++i) {
        #pragma unroll
        for (int r = 0; r < 4; ++r) {
            int row = m0 + wm + i * 16 + cr + r;
            long long base = (long long)row * ldc + n0 + wn + cc;
            #pragma unroll
            for (int j = 0; j < 4; ++j) {
                float v = acc[i][j][r];
                if (MODE == 0) Cf[base + j * 16] = v;
                if (MODE == 1) atomicAdd(Cf + base + j * 16, v);
                if (MODE == 2) Cs[base + j * 16] = f2bf(v);
            }
        }
    }
}

// ---------------- zero / copy helpers (float4-vectorized) ----------------
__global__ void zero_f32(float* __restrict__ p) {
    long long i = (long long)blockIdx.x * 256 + threadIdx.x;
    ((float4*)p)[i] = make_float4(0.f, 0.f, 0.f, 0.f);
}
__global__ void copy_f32(float* __restrict__ dst, const float* __restrict__ src) {
    long long i = (long long)blockIdx.x * 256 + threadIdx.x;
    ((float4*)dst)[i] = ((const float4*)src)[i];
}

// ---------------- QKV post: split heads, l2norm(q,k), RoPE -> bf16 [h][s][64] ----------------
__global__ __launch_bounds__(256) void qkv_post(const float* __restrict__ qkv,
                                                short* __restrict__ q,
                                                short* __restrict__ k) {
    int lane = threadIdx.x & 63;
    int sh = blockIdx.x * 4 + (threadIdx.x >> 6);
    int s = sh >> 4;
    int h = sh & 15;
    const float* base = qkv + (long long)s * 3 * DIM;
    float qv = base[h * HEADDIM + lane];
    float kv = base[DIM + h * HEADDIM + lane];
    float qs = qv * qv, ks = kv * kv;
    #pragma unroll
    for (int off = 32; off; off >>= 1) {
        qs += __shfl_xor(qs, off);
        ks += __shfl_xor(ks, off);
    }
    qv /= fmaxf(sqrtf(qs), EPS_);
    kv /= fmaxf(sqrtf(ks), EPS_);
    int i = lane & 31;
    float f = (float)s * powf(10000.0f, -(float)i / 32.0f);
    float c = cosf(f), sn = sinf(f);
    float qo = __shfl_xor(qv, 32);
    float ko = __shfl_xor(kv, 32);
    float sgn = (lane < 32) ? sn : -sn;
    float qr = qv * c + qo * sgn;
    float kr = kv * c + ko * sgn;
    long long o = ((long long)h * TOKENS + s) * HEADDIM + lane;
    q[o] = f2bf(qr);
    k[o] = f2bf(kr);
}

// ---------------- V transpose: qkv fp32 [s][3D] -> vt bf16 [h][64][2048] ----------------
__global__ __launch_bounds__(256) void vtrans(const float* __restrict__ qkv,
                                              short* __restrict__ vt) {
    int h = blockIdx.z;
    int s0 = blockIdx.x * 32, d0 = blockIdx.y * 32;
    __shared__ float t[32][33];
    int tx = threadIdx.x & 31, ty = threadIdx.x >> 5;
    #pragma unroll
    for (int r = ty; r < 32; r += 8)
        t[r][tx] = qkv[(long long)(s0 + r) * (3 * DIM) + 2 * DIM + h * HEADDIM + d0 + tx];
    __syncthreads();
    #pragma unroll
    for (int r = ty; r < 32; r += 8)
        vt[((long long)h * HEADDIM + d0 + r) * TOKENS + s0 + tx] = f2bf(t[tx][r]);
}

// ---------------- MFMA flash attention, key-split with store-based combine ----------------
// No-max softmax (safe: qk-norm bounds |s/8|<=~0.13) makes O/l partials plain
// sums over keys -> causal triangle split into uniform chunks of <=8 key-tiles
// (16 heads x 80 chunks = 1280 blocks). Chunk ch of a q-block writes partial O
// (fp32) to slice Oacc[ch] and partial l to lacc[ch] with PLAIN STORES (no
// cross-XCD atomic RMW). attn_norm sums the nch slices. One wave = 16 q-rows;
// K/V B-fragments loaded straight from global; no barriers; P via wave-private
// LDS (stride 68, bank-balanced).
#define PLD 68
__global__ __launch_bounds__(256, 2) void attn_kernel(const short* __restrict__ q,
                                                      const short* __restrict__ k,
                                                      const short* __restrict__ vt,
                                                      float* __restrict__ Oacc,
                                                      float* __restrict__ lacc) {
    const int w = threadIdx.x >> 6, lane = threadIdx.x & 63;
    const int col = lane & 15, quad = lane >> 4;
    const int head = blockIdx.x / 80;
    const int t = blockIdx.x % 80;
    int qb, ch;
    if (t < 8)       { qb = t;                ch = 0; }
    else if (t < 24) { qb = 8 + (t - 8) / 2;  ch = (t - 8) % 2; }
    else if (t < 48) { qb = 16 + (t - 24) / 3; ch = (t - 24) % 3; }
    else             { qb = 24 + (t - 48) / 4; ch = (t - 48) % 4; }
    const int nch = qb / 8 + 1;
    const int ntk = qb + 1;                       // causal key-tiles for this q-block
    const int per = (ntk + nch - 1) / nch;
    const int t0 = ch * per;
    const int t1 = (t0 + per < ntk) ? t0 + per : ntk;
    const int qbase = qb * 64 + w * 16;
    __shared__ short Ps[4 * 16 * PLD];
    short* Pw = Ps + w * 16 * PLD;
    const short* kh = k + (long long)head * TOKENS * HEADDIM;
    const short* vh = vt + (long long)head * HEADDIM * TOKENS;
    // Q fragments (A-layout): row = col, k = quad*8 (+32)
    bf8 qf[2];
    #pragma unroll
    for (int ks = 0; ks < 2; ++ks)
        qf[ks] = *(const bf8*)(q + ((long long)head * TOKENS + qbase + col) * HEADDIM + ks * 32 + quad * 8);
    f32x4 o_[4];
    float l_[4];
    #pragma unroll
    for (int n = 0; n < 4; ++n) { f32x4 z = {0.f, 0.f, 0.f, 0.f}; o_[n] = z; }
    #pragma unroll
    for (int r = 0; r < 4; ++r) l_[r] = 0.f;
    // preload K fragments for tile t0
    bf8 kfc[2][4];
    #pragma unroll
    for (int ks = 0; ks < 2; ++ks)
        #pragma unroll
        for (int nt = 0; nt < 4; ++nt)
            kfc[ks][nt] = *(const bf8*)(kh + (long long)(t0 * 64 + nt * 16 + col) * HEADDIM + ks * 32 + quad * 8);
    for (int kt = t0; kt < t1; ++kt) {
        const int j0 = kt * 64;
        // V loads for this tile + K loads for the next (latency hides under QK+softmax)
        bf8 vfc[2][4];
        #pragma unroll
        for (int ks = 0; ks < 2; ++ks)
            #pragma unroll
            for (int nt = 0; nt < 4; ++nt)
                vfc[ks][nt] = *(const bf8*)(vh + (long long)(nt * 16 + col) * TOKENS + j0 + ks * 32 + quad * 8);
        bf8 kfn[2][4];
        if (kt + 1 < t1) {
            #pragma unroll
            for (int ks = 0; ks < 2; ++ks)
                #pragma unroll
                for (int nt = 0; nt < 4; ++nt)
                    kfn[ks][nt] = *(const bf8*)(kh + (long long)(j0 + 64 + nt * 16 + col) * HEADDIM + ks * 32 + quad * 8);
        }
        // S = Q K^T  [16 q][64 keys]
        f32x4 sacc[4];
        #pragma unroll
        for (int n = 0; n < 4; ++n) { f32x4 z = {0.f, 0.f, 0.f, 0.f}; sacc[n] = z; }
        #pragma unroll
        for (int ks = 0; ks < 2; ++ks)
            #pragma unroll
            for (int nt = 0; nt < 4; ++nt)
                sacc[nt] = __builtin_amdgcn_mfma_f32_16x16x32_bf16(qf[ks], kfc[ks][nt], sacc[nt], 0, 0, 0);
        // p = exp(s/8); |s/8| <= ~0.13 (unit q,k) so no max-shift needed.
        const bool diag = (j0 + 64 > qbase);
        #pragma unroll
        for (int nt = 0; nt < 4; ++nt)
            #pragma unroll
            for (int r = 0; r < 4; ++r) {
                float p = __expf(sacc[nt][r] * 0.125f);
                if (diag && (j0 + nt * 16 + col > qbase + quad * 4 + r)) p = 0.f;
                l_[r] += p;
                Pw[(quad * 4 + r) * PLD + nt * 16 + col] = f2bf(p);
            }
        // O += P V
        #pragma unroll
        for (int ks = 0; ks < 2; ++ks) {
            bf8 pf = *(const bf8*)(Pw + col * PLD + ks * 32 + quad * 8);
            #pragma unroll
            for (int nt = 0; nt < 4; ++nt)
                o_[nt] = __builtin_amdgcn_mfma_f32_16x16x32_bf16(pf, vfc[ks][nt], o_[nt], 0, 0, 0);
        }
        #pragma unroll
        for (int ks = 0; ks < 2; ++ks)
            #pragma unroll
            for (int nt = 0; nt < 4; ++nt)
                kfc[ks][nt] = kfn[ks][nt];
    }
    // epilogue: plain stores of partials into slice ch (exact linear combine)
    float* Oc = Oacc + (long long)ch * (TOKENS * DIM);
    #pragma unroll
    for (int r = 0; r < 4; ++r) {
        int row = qbase + quad * 4 + r;
        float* op = Oc + (long long)row * DIM + head * HEADDIM;
        #pragma unroll
        for (int nt = 0; nt < 4; ++nt)
            op[nt * 16 + col] = o_[nt][r];
        float l = l_[r];
        #pragma unroll
        for (int off = 1; off < 16; off <<= 1) l += __shfl_xor(l, off);
        if (col == 0) lacc[ch * (TOKENS * NHEADS) + row * NHEADS + head] = l;
    }
}

// ---------------- Attention normalize: xo = sum_ch Oacc / sum_ch l -> bf16 ----------------
__global__ void attn_norm(const float* __restrict__ Oacc, const float* __restrict__ lacc,
                          short* __restrict__ xo) {
    long long i = (long long)blockIdx.x * 256 + threadIdx.x;  // 2M
    int row = (int)(i >> 10), col = (int)(i & 1023);
    int nch = (row >> 9) + 1;                // (row/64)/8 + 1
    int head = col >> 6;
    float so = 0.f, sl = 0.f;
    for (int c = 0; c < nch; ++c) {
        so += Oacc[(long long)c * (TOKENS * DIM) + i];
        sl += lacc[c * (TOKENS * NHEADS) + row * NHEADS + head];
    }
    xo[i] = f2bf(so / sl);
}

// ---------------- Router (bf16 x input) ----------------
__global__ __launch_bounds__(256) void router_kernel(const short* __restrict__ xf,
                                                     const float* __restrict__ keys_w,
                                                     const int* __restrict__ idx,
                                                     const float* __restrict__ vals,
                                                     float* __restrict__ w_route) {
    int t = blockIdx.x;
    int tid = threadIdx.x;
    int e = tid & 31, c = tid >> 5;
    const short* xr = xf + (long long)t * DIM;
    float p = 0.f;
    for (int j = 0; j < 128; ++j)
        p += bf2f(xr[c * 128 + j]) * keys_w[(c * 128 + j) * NEXP + e];
    __shared__ float part[8][32];
    part[c][e] = p;
    __syncthreads();
    if (tid < NEXP) {
        float lg = 0.f;
        #pragma unroll
        for (int cc = 0; cc < 8; ++cc) lg += part[cc][tid];
        part[0][tid] = lg;
    }
    __syncthreads();
    __shared__ float gate_s[TOPK];
    __shared__ int idx_s[TOPK];
    if (tid < TOPK) {
        int ii = idx[t * TOPK + tid];
        float g = vals[t * TOPK + tid] + part[0][ii];
        gate_s[tid] = (1.0f / (1.0f + __expf(-g))) * RSF_;
        idx_s[tid] = ii;
    }
    __syncthreads();
    if (tid < NEXP) {
        float wr = 0.f;
        #pragma unroll
        for (int kk = 0; kk < TOPK; ++kk)
            if (idx_s[kk] == tid) wr += gate_s[kk];
        w_route[(long long)t * NEXP + tid] = wr;
    }
}

// ---------------- h = silu(g) * u * w_route -> bf16 (gu bf16 [t][e*256 + {g:0-127,u:128-255}]) --
__global__ void moe_act_kernel(const short* __restrict__ gu, const float* __restrict__ w_route,
                               short* __restrict__ hb) {
    long long i = (long long)blockIdx.x * 256 + threadIdx.x;  // 8M = T*NEXP*EDIM
    int t = (int)(i >> 12);
    int e = (int)(i >> 7) & 31;
    int j = (int)(i & 127);
    float gv = bf2f(gu[(long long)t * (NEXP * 256) + e * 256 + j]);
    float uv = bf2f(gu[(long long)t * (NEXP * 256) + e * 256 + 128 + j]);
    float w = w_route[t * NEXP + e];
    float si = gv / (1.0f + __expf(-gv));
    hb[i] = f2bf(si * uv * w);
}

// ---------------- Shared-expert SwiGLU (bf16 in) -> bf16 ----------------
__global__ void swiglu_kernel(const short* __restrict__ up, short* __restrict__ hs) {
    long long i = (long long)blockIdx.x * 256 + threadIdx.x;  // 4M
    int t = (int)(i >> 11), j = (int)(i & 2047);
    float x1 = bf2f(up[(long long)t * (2 * DSHARED) + j]);
    float x2 = bf2f(up[(long long)t * (2 * DSHARED) + DSHARED + j]);
    hs[i] = f2bf(x1 / (1.0f + __expf(-x1)) * x2);
}

// ---------------- Final: out = y_moe + x_ffn_input ----------------
__global__ void final_add(const float* __restrict__ a, const float* __restrict__ b,
                          float* __restrict__ out) {
    long long i = (long long)blockIdx.x * 256 + threadIdx.x;  // 2M
    out[i] = a[i] + b[i];
}

extern "C" void kernel_launch(void* const* d_in, const int* in_sizes, int n_in,
                              void* d_out, int out_size, void* d_ws, size_t ws_size,
                              hipStream_t stream) {
    (void)in_sizes; (void)n_in; (void)out_size; (void)ws_size;
    const float* x_input     = (const float*)d_in[0];
    const int*   indices     = (const int*)d_in[1];
    const float* values      = (const float*)d_in[2];
    const float* w_attn      = (const float*)d_in[3];
    const float* w_attn_o    = (const float*)d_in[4];
    const float* attn_norm_w = (const float*)d_in[5];
    const float* ffn_norm_w  = (const float*)d_in[6];
    const float* ffn_experts = (const float*)d_in[7];
    const float* keys_w      = (const float*)d_in[8];
    const float* w_up        = (const float*)d_in[9];
    const float* w_down      = (const float*)d_in[10];
    float* out = (float*)d_out;
    float* ws  = (float*)d_ws;

    const long long M1 = 1024 * 1024;
    // Workspace (float units, lifetime-aliased; max extent 24M floats = 96MB):
    float* xffn    = ws + 0 * M1;                     // [0,2)   x_input + attn_o (atomic)
    float* ymoe    = ws + 2 * M1;                     // [2,4)   atomic accumulator
    short* xa_bf   = (short*)(ws + 4 * M1);           // [4,4.5)
    short* xf_bf   = (short*)(ws + 4 * M1 + M1 / 2);  // [4.5,5)
    short* xattn_bf= (short*)(ws + 5 * M1);           // [5,5.5)
    float* w_route = ws + 5 * M1 + M1 / 2;            // [5.5,5.6)
    float* qkv     = ws + 6 * M1;                     // [6,12)   phase A (dead after vtrans)
    float* Oacc    = ws + 6 * M1;                     // [6,14)   4 partial O slices (reuses qkv)
    float* lacc    = ws + 14 * M1;                    // [14,14.125) 4 x 2048 x 16
    short* qh_bf   = (short*)(ws + 15 * M1);          // [15,15.5)
    short* kh_bf   = (short*)(ws + 15 * M1 + M1 / 2); // [15.5,16)
    short* vt_bf   = (short*)(ws + 16 * M1);          // [16,16.5)
    short* wattn_t = (short*)(ws + 17 * M1);          // [17,18.5)
    short* wattno_t= (short*)(ws + 18 * M1 + M1 / 2); // [18.5,19)
    short* wgu     = (short*)(ws + 6 * M1);           // [6,10)   phase B (Oacc dead)
    short* gu_bf   = (short*)(ws + 10 * M1);          // [10,18)  (qh/kh/vt/wattn_t dead)
    short* h_bf    = (short*)(ws + 18 * M1);          // [18,22)  (wattno_t dead)
    short* w2t     = (short*)(ws + 22 * M1);          // [22,24)
    short* wupt    = (short*)(ws + 6 * M1);           // [6,8)    phase C (wgu dead)
    short* up_bf   = (short*)(ws + 10 * M1);          // [10,14)  (gu_bf dead)
    short* hs_bf   = (short*)(ws + 14 * M1);          // [14,16)  (lacc dead)
    short* wdownt  = (short*)(ws + 16 * M1);          // [16,17)

    const long long EXP_STRIDE = (long long)NEXP * DIM * EDIM;  // 4M

    // ---- phase A: attention ----
    tconv<<<dim3(3072 / 32, DIM / 32, 1), 256, 0, stream>>>(w_attn, 0, wattn_t, 0, DIM, 3 * DIM);
    rmsnorm_kernel<<<TOKENS, 256, 0, stream>>>(x_input, attn_norm_w, xa_bf);
    gemm_bf16<0><<<dim3(3072 / 128, TOKENS / 128, 1), 256, 0, stream>>>(
        xa_bf, DIM, 0, wattn_t, DIM, 0, qkv, 3 * DIM, 0, TOKENS, 3 * DIM, DIM);
    qkv_post<<<(TOKENS * NHEADS) / 4, 256, 0, stream>>>(qkv, qh_bf, kh_bf);
    vtrans<<<dim3(TOKENS / 32, HEADDIM / 32, NHEADS), 256, 0, stream>>>(qkv, vt_bf);
    attn_kernel<<<NHEADS * 80, 256, 0, stream>>>(qh_bf, kh_bf, vt_bf, Oacc, lacc);
    attn_norm<<<(TOKENS * DIM) / 256, 256, 0, stream>>>(Oacc, lacc, xattn_bf);
    tconv<<<dim3(DIM / 32, DIM / 32, 1), 256, 0, stream>>>(w_attn_o, 0, wattno_t, 0, DIM, DIM);
    copy_f32<<<(TOKENS * DIM) / 1024, 256, 0, stream>>>(xffn, x_input);   // residual pre-init
    gemm_bf16<1><<<dim3(DIM / 128, TOKENS / 128, 4), 256, 0, stream>>>(
        xattn_bf, DIM, 0, wattno_t, DIM, 0, xffn, DIM, 0, TOKENS, DIM, DIM);

    // ---- phase B: router + experts ----
    rmsnorm_kernel<<<TOKENS, 256, 0, stream>>>(xffn, ffn_norm_w, xf_bf);
    router_kernel<<<TOKENS, 256, 0, stream>>>(xf_bf, keys_w, indices, values, w_route);
    // Wgu[e] = [256][1024]: rows 0-127 = W0[e]^T, 128-255 = W1[e]^T
    tconv<<<dim3(EDIM / 32, DIM / 32, NEXP), 256, 0, stream>>>(
        ffn_experts, (long long)DIM * EDIM, wgu, 256 * 1024, DIM, EDIM);
    tconv<<<dim3(EDIM / 32, DIM / 32, NEXP), 256, 0, stream>>>(
        ffn_experts + EXP_STRIDE, (long long)DIM * EDIM, wgu + 128 * 1024, 256 * 1024, DIM, EDIM);
    gemm_bf16<2><<<dim3(2, TOKENS / 128, NEXP), 256, 0, stream>>>(
        xf_bf, DIM, 0, wgu, DIM, 256 * 1024, gu_bf, NEXP * 256, 256, TOKENS, 256, DIM);
    moe_act_kernel<<<(TOKENS * NEXP * EDIM) / 256, 256, 0, stream>>>(gu_bf, w_route, h_bf);
    w2conv<<<(NEXP * DIM * EDIM) / 256, 256, 0, stream>>>(ffn_experts + 2 * EXP_STRIDE, w2t);
    zero_f32<<<(TOKENS * DIM) / 1024, 256, 0, stream>>>(ymoe);
    gemm_bf16<1><<<dim3(DIM / 128, TOKENS / 128, 4), 256, 0, stream>>>(
        h_bf, NEXP * EDIM, 0, w2t, NEXP * EDIM, 0, ymoe, DIM, 0, TOKENS, DIM, NEXP * EDIM);

    // ---- phase C: shared expert ----
    tconv<<<dim3((2 * DSHARED) / 32, DIM / 32, 1), 256, 0, stream>>>(w_up, 0, wupt, 0, DIM, 2 * DSHARED);
    gemm_bf16<2><<<dim3((2 * DSHARED) / 128, TOKENS / 128, 1), 256, 0, stream>>>(
        xf_bf, DIM, 0, wupt, DIM, 0, up_bf, 2 * DSHARED, 0, TOKENS, 2 * DSHARED, DIM);
    swiglu_kernel<<<(TOKENS * DSHARED) / 256, 256, 0, stream>>>(up_bf, hs_bf);
    tconv<<<dim3(DIM / 32, DSHARED / 32, 1), 256, 0, stream>>>(w_down, 0, wdownt, 0, DSHARED, DIM);
    gemm_bf16<1><<<dim3(DIM / 128, TOKENS / 128, 4), 256, 0, stream>>>(
        hs_bf, DSHARED, 0, wdownt, DSHARED, 0, ymoe, DIM, 0, TOKENS, DIM, DSHARED);

    // ---- final residual ----
    final_add<<<(TOKENS * DIM) / 256, 256, 0, stream>>>(ymoe, xffn, out);
}

// Round 9
// 491.273 us; speedup vs baseline: 1.1035x; 1.0903x over previous
//
#include <hip/hip_runtime.h>
#include <math.h>

#define TOKENS 2048
#define DIM 1024
#define NHEADS 16
#define HEADDIM 64
#define NEXP 32
#define EDIM 128
#define TOPK 8
#define DSHARED 2048
#define RSF_ 2.5f
#define EPS_ 1e-6f

using bf8  = __attribute__((ext_vector_type(8))) short;   // 8 bf16 in 4 VGPRs
using f32x4 = __attribute__((ext_vector_type(4))) float;  // MFMA accumulator

__device__ __forceinline__ short f2bf(float f) {
    unsigned u = __float_as_uint(f);
    unsigned r = (u + 0x7fffu + ((u >> 16) & 1u)) >> 16;
    return (short)r;
}
__device__ __forceinline__ float bf2f(short s) {
    return __uint_as_float(((unsigned)(unsigned short)s) << 16);
}

// Direct global->LDS DMA, 16B per lane. LDS dest = wave-uniform base + lane*16.
__device__ __forceinline__ void async16(const short* g, const short* l) {
    __builtin_amdgcn_global_load_lds(
        (const __attribute__((address_space(1))) void*)(unsigned long long)g,
        (__attribute__((address_space(3))) void*)(unsigned)(unsigned long long)l,
        16, 0, 0);
}

// ---------------- RMSNorm: one block per token, bf16 output ----------------
__global__ __launch_bounds__(256) void rmsnorm_kernel(const float* __restrict__ x,
                                                      const float* __restrict__ w,
                                                      short* __restrict__ out) {
    int row = blockIdx.x;
    const float* xr = x + (long long)row * DIM;
    int t = threadIdx.x;
    float4 xv = ((const float4*)xr)[t];
    float ss = xv.x*xv.x + xv.y*xv.y + xv.z*xv.z + xv.w*xv.w;
    #pragma unroll
    for (int off = 32; off; off >>= 1) ss += __shfl_down(ss, off);
    __shared__ float warps[4];
    if ((t & 63) == 0) warps[t >> 6] = ss;
    __syncthreads();
    float tot = warps[0] + warps[1] + warps[2] + warps[3];
    float scale = rsqrtf(tot / (float)DIM + EPS_);
    float4 wv = ((const float4*)w)[t];
    short4 o;
    o.x = f2bf(xv.x * scale * wv.x);
    o.y = f2bf(xv.y * scale * wv.y);
    o.z = f2bf(xv.z * scale * wv.z);
    o.w = f2bf(xv.w * scale * wv.w);
    ((short4*)(out + (long long)row * DIM))[t] = o;
}

// ---------------- Transpose + convert: fp32 in[K][N] -> bf16 out[N][K] ----------------
__global__ __launch_bounds__(256) void tconv(const float* __restrict__ in, long long sin,
                                             short* __restrict__ out, long long sout,
                                             int K, int N) {
    in  += (long long)blockIdx.z * sin;
    out += (long long)blockIdx.z * sout;
    __shared__ float t[32][33];
    int n0 = blockIdx.x * 32, k0 = blockIdx.y * 32;
    int tx = threadIdx.x & 31, ty = threadIdx.x >> 5;  // ty 0..7
    #pragma unroll
    for (int r = ty; r < 32; r += 8)
        t[r][tx] = in[(long long)(k0 + r) * N + n0 + tx];
    __syncthreads();
    #pragma unroll
    for (int r = ty; r < 32; r += 8)
        out[(long long)(n0 + r) * K + k0 + tx] = f2bf(t[tx][r]);
}

// W2 [e][d][h] fp32 -> bf16 [d][(e*128+h)]
__global__ void w2conv(const float* __restrict__ in, short* __restrict__ out) {
    long long i = (long long)blockIdx.x * 256 + threadIdx.x;  // 4M
    int e = (int)(i >> 17);
    int d = (int)(i >> 7) & 1023;
    int h = (int)(i & 127);
    out[(long long)d * (NEXP * EDIM) + e * EDIM + h] = f2bf(in[i]);
}

// ---------------- bf16 MFMA GEMM: C[M][N] = A[M][K] @ Bt[N][K]^T ----------------
// 128x128 tile, BK=64, XOR-swizzled LDS (conflict-free ds_read_b128),
// async global->LDS staging.
// MODE 0: f32 store, z = batch.  MODE 1: f32 atomicAdd, z = K-split index.
// MODE 2: bf16 store, z = batch.
template<int MODE>
__global__ __launch_bounds__(256) void gemm_bf16(const short* __restrict__ A, int lda, long long sA,
                                                 const short* __restrict__ Bt, int ldb, long long sBt,
                                                 void* __restrict__ Cv, int ldc, long long sC,
                                                 int M, int N, int K) {
    int koff = 0, Ksub = K;
    if (MODE == 1) {
        Ksub = K / gridDim.z;
        koff = blockIdx.z * Ksub;
    } else {
        A  += (long long)blockIdx.z * sA;
        Bt += (long long)blockIdx.z * sBt;
    }
    float* Cf = (float*)Cv;
    short* Cs = (short*)Cv;
    if (MODE != 1) { Cf += (long long)blockIdx.z * sC; Cs += (long long)blockIdx.z * sC; }
    const int m0 = blockIdx.y * 128, n0 = blockIdx.x * 128;
    __shared__ short As[128 * 64];
    __shared__ short Bs[128 * 64];
    const int tid = threadIdx.x, lane = tid & 63, w = tid >> 6;
    const int wm = (w >> 1) * 64, wn = (w & 1) * 64;
    const int drow = lane >> 3;                  // 0..7
    const int dcol = ((lane & 7) ^ drow) * 8;    // swizzled 16B-chunk col, shorts
    const short* ag = A + (long long)(m0 + w * 32 + drow) * lda + koff + dcol;
    const short* bg = Bt + (long long)(n0 + w * 32 + drow) * ldb + koff + dcol;
    const short* lA = As + w * 32 * 64;
    const short* lB = Bs + w * 32 * 64;
    f32x4 acc[4][4];
    #pragma unroll
    for (int i = 0; i < 4; ++i)
        #pragma unroll
        for (int j = 0; j < 4; ++j) { f32x4 z = {0.f, 0.f, 0.f, 0.f}; acc[i][j] = z; }
    const int ra = lane & 15, quad = lane >> 4;
    const int fs0 = ((quad + 0) ^ (ra & 7)) * 8;
    const int fs1 = ((quad + 4) ^ (ra & 7)) * 8;
    for (int k0 = 0; k0 < Ksub; k0 += 64) {
        #pragma unroll
        for (int c = 0; c < 4; ++c) {
            async16(ag + (long long)(c * 8) * lda + k0, lA + c * 512);
            async16(bg + (long long)(c * 8) * ldb + k0, lB + c * 512);
        }
        __syncthreads();   // drains vmcnt -> tiles resident
        #pragma unroll
        for (int h = 0; h < 2; ++h) {
            const int fs = h ? fs1 : fs0;
            bf8 af[4], bfv[4];
            #pragma unroll
            for (int i = 0; i < 4; ++i) af[i]  = *(const bf8*)(As + (wm + i * 16 + ra) * 64 + fs);
            #pragma unroll
            for (int j = 0; j < 4; ++j) bfv[j] = *(const bf8*)(Bs + (wn + j * 16 + ra) * 64 + fs);
            #pragma unroll
            for (int i = 0; i < 4; ++i)
                #pragma unroll
                for (int j = 0; j < 4; ++j)
                    acc[i][j] = __builtin_amdgcn_mfma_f32_16x16x32_bf16(af[i], bfv[j], acc[i][j], 0, 0, 0);
        }
        __syncthreads();   // reads done before next DMA overwrites
    }
    const int cr = quad * 4, cc = ra;
    #pragma unroll
    for (int i = 0; i < 4; ++i) {
        #pragma unroll
        for (int r = 0; r < 4; ++r) {
            int row = m0 + wm + i * 16 + cr + r;
            long long base = (long long)row * ldc + n0 + wn + cc;
            #pragma unroll
            for (int j = 0; j < 4; ++j) {
                float v = acc[i][j][r];
                if (MODE == 0) Cf[base + j * 16] = v;
                if (MODE == 1) atomicAdd(Cf + base + j * 16, v);
                if (MODE == 2) Cs[base + j * 16] = f2bf(v);
            }
        }
    }
}

// ---------------- zero / copy helpers (float4-vectorized) ----------------
__global__ void zero_f32(float* __restrict__ p) {
    long long i = (long long)blockIdx.x * 256 + threadIdx.x;
    ((float4*)p)[i] = make_float4(0.f, 0.f, 0.f, 0.f);
}
__global__ void copy_f32(float* __restrict__ dst, const float* __restrict__ src) {
    long long i = (long long)blockIdx.x * 256 + threadIdx.x;
    ((float4*)dst)[i] = ((const float4*)src)[i];
}

// ---------------- QKV post (bf16 qkv): split heads, l2norm(q,k), RoPE -> bf16 [h][s][64] ----
__global__ __launch_bounds__(256) void qkv_post(const short* __restrict__ qkv,
                                                short* __restrict__ q,
                                                short* __restrict__ k) {
    int lane = threadIdx.x & 63;
    int sh = blockIdx.x * 4 + (threadIdx.x >> 6);
    int s = sh >> 4;
    int h = sh & 15;
    const short* base = qkv + (long long)s * 3 * DIM;
    float qv = bf2f(base[h * HEADDIM + lane]);
    float kv = bf2f(base[DIM + h * HEADDIM + lane]);
    float qs = qv * qv, ks = kv * kv;
    #pragma unroll
    for (int off = 32; off; off >>= 1) {
        qs += __shfl_xor(qs, off);
        ks += __shfl_xor(ks, off);
    }
    qv /= fmaxf(sqrtf(qs), EPS_);
    kv /= fmaxf(sqrtf(ks), EPS_);
    int i = lane & 31;
    float f = (float)s * powf(10000.0f, -(float)i / 32.0f);
    float c = cosf(f), sn = sinf(f);
    float qo = __shfl_xor(qv, 32);
    float ko = __shfl_xor(kv, 32);
    float sgn = (lane < 32) ? sn : -sn;
    float qr = qv * c + qo * sgn;
    float kr = kv * c + ko * sgn;
    long long o = ((long long)h * TOKENS + s) * HEADDIM + lane;
    q[o] = f2bf(qr);
    k[o] = f2bf(kr);
}

// ---------------- V transpose (bf16 qkv): [s][3D] -> vt bf16 [h][64][2048] ----------------
__global__ __launch_bounds__(256) void vtrans(const short* __restrict__ qkv,
                                              short* __restrict__ vt) {
    int h = blockIdx.z;
    int s0 = blockIdx.x * 32, d0 = blockIdx.y * 32;
    __shared__ short t[32][34];
    int tx = threadIdx.x & 31, ty = threadIdx.x >> 5;
    #pragma unroll
    for (int r = ty; r < 32; r += 8)
        t[r][tx] = qkv[(long long)(s0 + r) * (3 * DIM) + 2 * DIM + h * HEADDIM + d0 + tx];
    __syncthreads();
    #pragma unroll
    for (int r = ty; r < 32; r += 8)
        vt[((long long)h * HEADDIM + d0 + r) * TOKENS + s0 + tx] = t[tx][r];
}

// ---------------- MFMA flash attention: LDS-staged K/V (DMA), key-split combine ----------
// K/V tiles staged per-block via global_load_lds (no VGPR prefetch for the
// compiler to sink; 4 waves share one tile copy). XOR source-swizzle makes the
// ds_read_b128 fragment reads 2-way conflict-free. No-max softmax (qk-norm
// bounds |s/8|<=~0.13) keeps O/l partials linear; causal triangle split into
// chunks of <=8 key-tiles (16 heads x 80 chunks); partials combined via plain
// stores into per-chunk slices + attn_norm reduction.
#define PLD 68
__global__ __launch_bounds__(256) void attn_kernel(const short* __restrict__ q,
                                                   const short* __restrict__ k,
                                                   const short* __restrict__ vt,
                                                   float* __restrict__ Oacc,
                                                   float* __restrict__ lacc) {
    const int w = threadIdx.x >> 6, lane = threadIdx.x & 63;
    const int col = lane & 15, quad = lane >> 4;
    const int head = blockIdx.x / 80;
    const int t = blockIdx.x % 80;
    int qb, ch;
    if (t < 8)       { qb = t;                ch = 0; }
    else if (t < 24) { qb = 8 + (t - 8) / 2;  ch = (t - 8) % 2; }
    else if (t < 48) { qb = 16 + (t - 24) / 3; ch = (t - 24) % 3; }
    else             { qb = 24 + (t - 48) / 4; ch = (t - 48) % 4; }
    const int nch = qb / 8 + 1;
    const int ntk = qb + 1;
    const int per = (ntk + nch - 1) / nch;
    const int t0 = ch * per;
    const int t1 = (t0 + per < ntk) ? t0 + per : ntk;
    const int qbase = qb * 64 + w * 16;
    __shared__ short Ks[64 * 64];
    __shared__ short Vs[64 * 64];
    __shared__ short Ps[4 * 16 * PLD];
    short* Pw = Ps + w * 16 * PLD;
    const short* kh = k + (long long)head * TOKENS * HEADDIM;
    const short* vh = vt + (long long)head * HEADDIM * TOKENS;
    // DMA lane mapping: row-of-8 = lane>>3, 16B chunk = lane&7, source column
    // XOR-swizzled by row so LDS(row, c) holds global chunk c^(row&7).
    const int r8 = lane >> 3;
    const int sw = ((lane & 7) ^ r8) * 8;     // swizzled source col, shorts
    // Q fragments (A-layout): row = col, k = quad*8 (+32)
    bf8 qf[2];
    #pragma unroll
    for (int ks = 0; ks < 2; ++ks)
        qf[ks] = *(const bf8*)(q + ((long long)head * TOKENS + qbase + col) * HEADDIM + ks * 32 + quad * 8);
    // fragment LDS chunk offsets: global chunk g=ks*4+quad lives at (g^(col&7))
    const int fo0 = (((0 * 4) + quad) ^ (col & 7)) * 8;
    const int fo1 = (((1 * 4) + quad) ^ (col & 7)) * 8;
    f32x4 o_[4];
    float l_[4];
    #pragma unroll
    for (int n = 0; n < 4; ++n) { f32x4 z = {0.f, 0.f, 0.f, 0.f}; o_[n] = z; }
    #pragma unroll
    for (int r = 0; r < 4; ++r) l_[r] = 0.f;
    for (int kt = t0; kt < t1; ++kt) {
        const int j0 = kt * 64;
        // stage K[64 keys][64 d] and Vt[64 d][64 keys] tiles: wave w covers
        // rows w*16 + c*8 + r8 (c = 0,1), 16B per lane, source-swizzled.
        #pragma unroll
        for (int c = 0; c < 2; ++c) {
            int row = w * 16 + c * 8 + r8;
            async16(kh + (long long)(j0 + row) * HEADDIM + sw, Ks + (w * 16 + c * 8) * 64 + lane * 8);
            async16(vh + (long long)row * TOKENS + j0 + sw, Vs + (w * 16 + c * 8) * 64 + lane * 8);
        }
        __syncthreads();   // DMA drained -> tiles resident
        // S = Q K^T  [16 q][64 keys]
        f32x4 sacc[4];
        #pragma unroll
        for (int n = 0; n < 4; ++n) { f32x4 z = {0.f, 0.f, 0.f, 0.f}; sacc[n] = z; }
        #pragma unroll
        for (int ks = 0; ks < 2; ++ks) {
            const int fo = ks ? fo1 : fo0;
            #pragma unroll
            for (int nt = 0; nt < 4; ++nt) {
                bf8 kf = *(const bf8*)(Ks + (nt * 16 + col) * 64 + fo);
                sacc[nt] = __builtin_amdgcn_mfma_f32_16x16x32_bf16(qf[ks], kf, sacc[nt], 0, 0, 0);
            }
        }
        // p = exp(s/8); |s/8| <= ~0.13 (unit q,k) so no max-shift needed.
        const bool diag = (j0 + 64 > qbase);
        #pragma unroll
        for (int nt = 0; nt < 4; ++nt)
            #pragma unroll
            for (int r = 0; r < 4; ++r) {
                float p = __expf(sacc[nt][r] * 0.125f);
                if (diag && (j0 + nt * 16 + col > qbase + quad * 4 + r)) p = 0.f;
                l_[r] += p;
                Pw[(quad * 4 + r) * PLD + nt * 16 + col] = f2bf(p);
            }
        // O += P V
        #pragma unroll
        for (int ks = 0; ks < 2; ++ks) {
            bf8 pf = *(const bf8*)(Pw + col * PLD + ks * 32 + quad * 8);
            const int fo = ks ? fo1 : fo0;
            #pragma unroll
            for (int nt = 0; nt < 4; ++nt) {
                bf8 vf = *(const bf8*)(Vs + (nt * 16 + col) * 64 + fo);
                o_[nt] = __builtin_amdgcn_mfma_f32_16x16x32_bf16(pf, vf, o_[nt], 0, 0, 0);
            }
        }
        __syncthreads();   // all reads done before next tile's DMA overwrites
    }
    // epilogue: plain stores of partials into slice ch (exact linear combine)
    float* Oc = Oacc + (long long)ch * (TOKENS * DIM);
    #pragma unroll
    for (int r = 0; r < 4; ++r) {
        int row = qbase + quad * 4 + r;
        float* op = Oc + (long long)row * DIM + head * HEADDIM;
        #pragma unroll
        for (int nt = 0; nt < 4; ++nt)
            op[nt * 16 + col] = o_[nt][r];
        float l = l_[r];
        #pragma unroll
        for (int off = 1; off < 16; off <<= 1) l += __shfl_xor(l, off);
        if (col == 0) lacc[ch * (TOKENS * NHEADS) + row * NHEADS + head] = l;
    }
}

// ---------------- Attention normalize: xo = sum_ch Oacc / sum_ch l -> bf16 ----------------
__global__ void attn_norm(const float* __restrict__ Oacc, const float* __restrict__ lacc,
                          short* __restrict__ xo) {
    long long i = (long long)blockIdx.x * 256 + threadIdx.x;  // 2M
    int row = (int)(i >> 10), col = (int)(i & 1023);
    int nch = (row >> 9) + 1;                // (row/64)/8 + 1
    int head = col >> 6;
    float so = 0.f, sl = 0.f;
    for (int c = 0; c < nch; ++c) {
        so += Oacc[(long long)c * (TOKENS * DIM) + i];
        sl += lacc[c * (TOKENS * NHEADS) + row * NHEADS + head];
    }
    xo[i] = f2bf(so / sl);
}

// ---------------- Router (bf16 x input) ----------------
__global__ __launch_bounds__(256) void router_kernel(const short* __restrict__ xf,
                                                     const float* __restrict__ keys_w,
                                                     const int* __restrict__ idx,
                                                     const float* __restrict__ vals,
                                                     float* __restrict__ w_route) {
    int t = blockIdx.x;
    int tid = threadIdx.x;
    int e = tid & 31, c = tid >> 5;
    const short* xr = xf + (long long)t * DIM;
    float p = 0.f;
    for (int j = 0; j < 128; ++j)
        p += bf2f(xr[c * 128 + j]) * keys_w[(c * 128 + j) * NEXP + e];
    __shared__ float part[8][32];
    part[c][e] = p;
    __syncthreads();
    if (tid < NEXP) {
        float lg = 0.f;
        #pragma unroll
        for (int cc = 0; cc < 8; ++cc) lg += part[cc][tid];
        part[0][tid] = lg;
    }
    __syncthreads();
    __shared__ float gate_s[TOPK];
    __shared__ int idx_s[TOPK];
    if (tid < TOPK) {
        int ii = idx[t * TOPK + tid];
        float g = vals[t * TOPK + tid] + part[0][ii];
        gate_s[tid] = (1.0f / (1.0f + __expf(-g))) * RSF_;
        idx_s[tid] = ii;
    }
    __syncthreads();
    if (tid < NEXP) {
        float wr = 0.f;
        #pragma unroll
        for (int kk = 0; kk < TOPK; ++kk)
            if (idx_s[kk] == tid) wr += gate_s[kk];
        w_route[(long long)t * NEXP + tid] = wr;
    }
}

// ---------------- h = silu(g) * u * w_route -> bf16 (gu bf16 [t][e*256 + {g:0-127,u:128-255}]) --
__global__ void moe_act_kernel(const short* __restrict__ gu, const float* __restrict__ w_route,
                               short* __restrict__ hb) {
    long long i = (long long)blockIdx.x * 256 + threadIdx.x;  // 8M = T*NEXP*EDIM
    int t = (int)(i >> 12);
    int e = (int)(i >> 7) & 31;
    int j = (int)(i & 127);
    float gv = bf2f(gu[(long long)t * (NEXP * 256) + e * 256 + j]);
    float uv = bf2f(gu[(long long)t * (NEXP * 256) + e * 256 + 128 + j]);
    float w = w_route[t * NEXP + e];
    float si = gv / (1.0f + __expf(-gv));
    hb[i] = f2bf(si * uv * w);
}

// ---------------- Shared-expert SwiGLU (bf16 in) -> bf16 ----------------
__global__ void swiglu_kernel(const short* __restrict__ up, short* __restrict__ hs) {
    long long i = (long long)blockIdx.x * 256 + threadIdx.x;  // 4M
    int t = (int)(i >> 11), j = (int)(i & 2047);
    float x1 = bf2f(up[(long long)t * (2 * DSHARED) + j]);
    float x2 = bf2f(up[(long long)t * (2 * DSHARED) + DSHARED + j]);
    hs[i] = f2bf(x1 / (1.0f + __expf(-x1)) * x2);
}

// ---------------- Final: out = y_moe + x_ffn_input ----------------
__global__ void final_add(const float* __restrict__ a, const float* __restrict__ b,
                          float* __restrict__ out) {
    long long i = (long long)blockIdx.x * 256 + threadIdx.x;  // 2M
    out[i] = a[i] + b[i];
}

extern "C" void kernel_launch(void* const* d_in, const int* in_sizes, int n_in,
                              void* d_out, int out_size, void* d_ws, size_t ws_size,
                              hipStream_t stream) {
    (void)in_sizes; (void)n_in; (void)out_size; (void)ws_size;
    const float* x_input     = (const float*)d_in[0];
    const int*   indices     = (const int*)d_in[1];
    const float* values      = (const float*)d_in[2];
    const float* w_attn      = (const float*)d_in[3];
    const float* w_attn_o    = (const float*)d_in[4];
    const float* attn_norm_w = (const float*)d_in[5];
    const float* ffn_norm_w  = (const float*)d_in[6];
    const float* ffn_experts = (const float*)d_in[7];
    const float* keys_w      = (const float*)d_in[8];
    const float* w_up        = (const float*)d_in[9];
    const float* w_down      = (const float*)d_in[10];
    float* out = (float*)d_out;
    float* ws  = (float*)d_ws;

    const long long M1 = 1024 * 1024;
    // Workspace (float units, lifetime-aliased; max extent 24M floats = 96MB):
    float* xffn    = ws + 0 * M1;                     // [0,2)   x_input + attn_o (atomic)
    float* ymoe    = ws + 2 * M1;                     // [2,4)   atomic accumulator
    short* xa_bf   = (short*)(ws + 4 * M1);           // [4,4.5)
    short* xf_bf   = (short*)(ws + 4 * M1 + M1 / 2);  // [4.5,5)
    short* xattn_bf= (short*)(ws + 5 * M1);           // [5,5.5)
    float* w_route = ws + 5 * M1 + M1 / 2;            // [5.5,5.6)
    short* qkv_bf  = (short*)(ws + 6 * M1);           // [6,9)    phase A (dead after vtrans)
    float* Oacc    = ws + 6 * M1;                     // [6,14)   4 partial O slices (reuses qkv)
    float* lacc    = ws + 14 * M1;                    // [14,14.125) 4 x 2048 x 16
    short* qh_bf   = (short*)(ws + 15 * M1);          // [15,15.5)
    short* kh_bf   = (short*)(ws + 15 * M1 + M1 / 2); // [15.5,16)
    short* vt_bf   = (short*)(ws + 16 * M1);          // [16,16.5)
    short* wattn_t = (short*)(ws + 17 * M1);          // [17,18.5)
    short* wattno_t= (short*)(ws + 18 * M1 + M1 / 2); // [18.5,19)
    short* wgu     = (short*)(ws + 6 * M1);           // [6,10)   phase B (Oacc dead)
    short* gu_bf   = (short*)(ws + 10 * M1);          // [10,18)  (qh/kh/vt/wattn_t dead)
    short* h_bf    = (short*)(ws + 18 * M1);          // [18,22)  (wattno_t dead)
    short* w2t     = (short*)(ws + 22 * M1);          // [22,24)
    short* wupt    = (short*)(ws + 6 * M1);           // [6,8)    phase C (wgu dead)
    short* up_bf   = (short*)(ws + 10 * M1);          // [10,14)  (gu_bf dead)
    short* hs_bf   = (short*)(ws + 14 * M1);          // [14,16)  (lacc dead)
    short* wdownt  = (short*)(ws + 16 * M1);          // [16,17)

    const long long EXP_STRIDE = (long long)NEXP * DIM * EDIM;  // 4M

    // ---- phase A: attention ----
    tconv<<<dim3(3072 / 32, DIM / 32, 1), 256, 0, stream>>>(w_attn, 0, wattn_t, 0, DIM, 3 * DIM);
    rmsnorm_kernel<<<TOKENS, 256, 0, stream>>>(x_input, attn_norm_w, xa_bf);
    gemm_bf16<2><<<dim3(3072 / 128, TOKENS / 128, 1), 256, 0, stream>>>(
        xa_bf, DIM, 0, wattn_t, DIM, 0, qkv_bf, 3 * DIM, 0, TOKENS, 3 * DIM, DIM);
    qkv_post<<<(TOKENS * NHEADS) / 4, 256, 0, stream>>>(qkv_bf, qh_bf, kh_bf);
    vtrans<<<dim3(TOKENS / 32, HEADDIM / 32, NHEADS), 256, 0, stream>>>(qkv_bf, vt_bf);
    attn_kernel<<<NHEADS * 80, 256, 0, stream>>>(qh_bf, kh_bf, vt_bf, Oacc, lacc);
    attn_norm<<<(TOKENS * DIM) / 256, 256, 0, stream>>>(Oacc, lacc, xattn_bf);
    tconv<<<dim3(DIM / 32, DIM / 32, 1), 256, 0, stream>>>(w_attn_o, 0, wattno_t, 0, DIM, DIM);
    copy_f32<<<(TOKENS * DIM) / 1024, 256, 0, stream>>>(xffn, x_input);   // residual pre-init
    gemm_bf16<1><<<dim3(DIM / 128, TOKENS / 128, 4), 256, 0, stream>>>(
        xattn_bf, DIM, 0, wattno_t, DIM, 0, xffn, DIM, 0, TOKENS, DIM, DIM);

    // ---- phase B: router + experts ----
    rmsnorm_kernel<<<TOKENS, 256, 0, stream>>>(xffn, ffn_norm_w, xf_bf);
    router_kernel<<<TOKENS, 256, 0, stream>>>(xf_bf, keys_w, indices, values, w_route);
    // Wgu[e] = [256][1024]: rows 0-127 = W0[e]^T, 128-255 = W1[e]^T
    tconv<<<dim3(EDIM / 32, DIM / 32, NEXP), 256, 0, stream>>>(
        ffn_experts, (long long)DIM * EDIM, wgu, 256 * 1024, DIM, EDIM);
    tconv<<<dim3(EDIM / 32, DIM / 32, NEXP), 256, 0, stream>>>(
        ffn_experts + EXP_STRIDE, (long long)DIM * EDIM, wgu + 128 * 1024, 256 * 1024, DIM, EDIM);
    gemm_bf16<2><<<dim3(2, TOKENS / 128, NEXP), 256, 0, stream>>>(
        xf_bf, DIM, 0, wgu, DIM, 256 * 1024, gu_bf, NEXP * 256, 256, TOKENS, 256, DIM);
    moe_act_kernel<<<(TOKENS * NEXP * EDIM) / 256, 256, 0, stream>>>(gu_bf, w_route, h_bf);
    w2conv<<<(NEXP * DIM * EDIM) / 256, 256, 0, stream>>>(ffn_experts + 2 * EXP_STRIDE, w2t);
    zero_f32<<<(TOKENS * DIM) / 1024, 256, 0, stream>>>(ymoe);
    gemm_bf16<1><<<dim3(DIM / 128, TOKENS / 128, 4), 256, 0, stream>>>(
        h_bf, NEXP * EDIM, 0, w2t, NEXP * EDIM, 0, ymoe, DIM, 0, TOKENS, DIM, NEXP * EDIM);

    // ---- phase C: shared expert ----
    tconv<<<dim3((2 * DSHARED) / 32, DIM / 32, 1), 256, 0, stream>>>(w_up, 0, wupt, 0, DIM, 2 * DSHARED);
    gemm_bf16<2><<<dim3((2 * DSHARED) / 128, TOKENS / 128, 1), 256, 0, stream>>>(
        xf_bf, DIM, 0, wupt, DIM, 0, up_bf, 2 * DSHARED, 0, TOKENS, 2 * DSHARED, DIM);
    swiglu_kernel<<<(TOKENS * DSHARED) / 256, 256, 0, stream>>>(up_bf, hs_bf);
    tconv<<<dim3(DIM / 32, DSHARED / 32, 1), 256, 0, stream>>>(w_down, 0, wdownt, 0, DSHARED, DIM);
    gemm_bf16<1><<<dim3(DIM / 128, TOKENS / 128, 4), 256, 0, stream>>>(
        hs_bf, DSHARED, 0, wdownt, DSHARED, 0, ymoe, DIM, 0, TOKENS, DIM, DSHARED);

    // ---- final residual ----
    final_add<<<(TOKENS * DIM) / 256, 256, 0, stream>>>(ymoe, xffn, out);
}

// Round 10
// 444.551 us; speedup vs baseline: 1.2194x; 1.1051x over previous
//
#include <hip/hip_runtime.h>
#include <math.h>

#define TOKENS 2048
#define DIM 1024
#define NHEADS 16
#define HEADDIM 64
#define NEXP 32
#define EDIM 128
#define TOPK 8
#define DSHARED 2048
#define RSF_ 2.5f
#define EPS_ 1e-6f

using bf8  = __attribute__((ext_vector_type(8))) short;   // 8 bf16 in 4 VGPRs
using f32x4 = __attribute__((ext_vector_type(4))) float;  // MFMA accumulator

__device__ __forceinline__ short f2bf(float f) {
    unsigned u = __float_as_uint(f);
    unsigned r = (u + 0x7fffu + ((u >> 16) & 1u)) >> 16;
    return (short)r;
}
__device__ __forceinline__ float bf2f(short s) {
    return __uint_as_float(((unsigned)(unsigned short)s) << 16);
}

// Direct global->LDS DMA, 16B per lane. LDS dest = wave-uniform base + lane*16.
__device__ __forceinline__ void async16(const short* g, const short* l) {
    __builtin_amdgcn_global_load_lds(
        (const __attribute__((address_space(1))) void*)(unsigned long long)g,
        (__attribute__((address_space(3))) void*)(unsigned)(unsigned long long)l,
        16, 0, 0);
}

// ---------------- RMSNorm: one block per token, bf16 output ----------------
__global__ __launch_bounds__(256) void rmsnorm_kernel(const float* __restrict__ x,
                                                      const float* __restrict__ w,
                                                      short* __restrict__ out) {
    int row = blockIdx.x;
    const float* xr = x + (long long)row * DIM;
    int t = threadIdx.x;
    float4 xv = ((const float4*)xr)[t];
    float ss = xv.x*xv.x + xv.y*xv.y + xv.z*xv.z + xv.w*xv.w;
    #pragma unroll
    for (int off = 32; off; off >>= 1) ss += __shfl_down(ss, off);
    __shared__ float warps[4];
    if ((t & 63) == 0) warps[t >> 6] = ss;
    __syncthreads();
    float tot = warps[0] + warps[1] + warps[2] + warps[3];
    float scale = rsqrtf(tot / (float)DIM + EPS_);
    float4 wv = ((const float4*)w)[t];
    short4 o;
    o.x = f2bf(xv.x * scale * wv.x);
    o.y = f2bf(xv.y * scale * wv.y);
    o.z = f2bf(xv.z * scale * wv.z);
    o.w = f2bf(xv.w * scale * wv.w);
    ((short4*)(out + (long long)row * DIM))[t] = o;
}

// ---------------- Transpose + convert: fp32 in[K][N] -> bf16 out[N][K] ----------------
__global__ __launch_bounds__(256) void tconv(const float* __restrict__ in, long long sin,
                                             short* __restrict__ out, long long sout,
                                             int K, int N) {
    in  += (long long)blockIdx.z * sin;
    out += (long long)blockIdx.z * sout;
    __shared__ float t[32][33];
    int n0 = blockIdx.x * 32, k0 = blockIdx.y * 32;
    int tx = threadIdx.x & 31, ty = threadIdx.x >> 5;  // ty 0..7
    #pragma unroll
    for (int r = ty; r < 32; r += 8)
        t[r][tx] = in[(long long)(k0 + r) * N + n0 + tx];
    __syncthreads();
    #pragma unroll
    for (int r = ty; r < 32; r += 8)
        out[(long long)(n0 + r) * K + k0 + tx] = f2bf(t[tx][r]);
}

// W2 [e][d][h] fp32 -> bf16 [d][(e*128+h)]
__global__ void w2conv(const float* __restrict__ in, short* __restrict__ out) {
    long long i = (long long)blockIdx.x * 256 + threadIdx.x;  // 4M
    int e = (int)(i >> 17);
    int d = (int)(i >> 7) & 1023;
    int h = (int)(i & 127);
    out[(long long)d * (NEXP * EDIM) + e * EDIM + h] = f2bf(in[i]);
}

// ---------------- bf16 MFMA GEMM: C[M][N] = A[M][K] @ Bt[N][K]^T ----------------
// 128x128 tile, BK=64, XOR-swizzled LDS (conflict-free ds_read_b128),
// async global->LDS staging.
// MODE 0: f32 store, z = batch.     MODE 2: bf16 store, z = batch.
// MODE 3: f32 store, z = K-split slice (sC = slice stride). No atomics.
// MODE 4: f32 read+add+store, z = K-split slice (block-exclusive tiles).
template<int MODE>
__global__ __launch_bounds__(256) void gemm_bf16(const short* __restrict__ A, int lda, long long sA,
                                                 const short* __restrict__ Bt, int ldb, long long sBt,
                                                 void* __restrict__ Cv, int ldc, long long sC,
                                                 int M, int N, int K) {
    int koff = 0, Ksub = K;
    if (MODE >= 3) {
        Ksub = K / gridDim.z;
        koff = blockIdx.z * Ksub;
    } else {
        A  += (long long)blockIdx.z * sA;
        Bt += (long long)blockIdx.z * sBt;
    }
    float* Cf = (float*)Cv;
    short* Cs = (short*)Cv;
    Cf += (long long)blockIdx.z * sC;
    Cs += (long long)blockIdx.z * sC;
    const int m0 = blockIdx.y * 128, n0 = blockIdx.x * 128;
    __shared__ short As[128 * 64];
    __shared__ short Bs[128 * 64];
    const int tid = threadIdx.x, lane = tid & 63, w = tid >> 6;
    const int wm = (w >> 1) * 64, wn = (w & 1) * 64;
    const int drow = lane >> 3;                  // 0..7
    const int dcol = ((lane & 7) ^ drow) * 8;    // swizzled 16B-chunk col, shorts
    const short* ag = A + (long long)(m0 + w * 32 + drow) * lda + koff + dcol;
    const short* bg = Bt + (long long)(n0 + w * 32 + drow) * ldb + koff + dcol;
    const short* lA = As + w * 32 * 64;
    const short* lB = Bs + w * 32 * 64;
    f32x4 acc[4][4];
    #pragma unroll
    for (int i = 0; i < 4; ++i)
        #pragma unroll
        for (int j = 0; j < 4; ++j) { f32x4 z = {0.f, 0.f, 0.f, 0.f}; acc[i][j] = z; }
    const int ra = lane & 15, quad = lane >> 4;
    const int fs0 = ((quad + 0) ^ (ra & 7)) * 8;
    const int fs1 = ((quad + 4) ^ (ra & 7)) * 8;
    for (int k0 = 0; k0 < Ksub; k0 += 64) {
        #pragma unroll
        for (int c = 0; c < 4; ++c) {
            async16(ag + (long long)(c * 8) * lda + k0, lA + c * 512);
            async16(bg + (long long)(c * 8) * ldb + k0, lB + c * 512);
        }
        __syncthreads();   // drains vmcnt -> tiles resident
        #pragma unroll
        for (int h = 0; h < 2; ++h) {
            const int fs = h ? fs1 : fs0;
            bf8 af[4], bfv[4];
            #pragma unroll
            for (int i = 0; i < 4; ++i) af[i]  = *(const bf8*)(As + (wm + i * 16 + ra) * 64 + fs);
            #pragma unroll
            for (int j = 0; j < 4; ++j) bfv[j] = *(const bf8*)(Bs + (wn + j * 16 + ra) * 64 + fs);
            #pragma unroll
            for (int i = 0; i < 4; ++i)
                #pragma unroll
                for (int j = 0; j < 4; ++j)
                    acc[i][j] = __builtin_amdgcn_mfma_f32_16x16x32_bf16(af[i], bfv[j], acc[i][j], 0, 0, 0);
        }
        __syncthreads();   // reads done before next DMA overwrites
    }
    const int cr = quad * 4, cc = ra;
    #pragma unroll
    for (int i = 0; i < 4; ++i) {
        #pragma unroll
        for (int r = 0; r < 4; ++r) {
            int row = m0 + wm + i * 16 + cr + r;
            long long base = (long long)row * ldc + n0 + wn + cc;
            #pragma unroll
            for (int j = 0; j < 4; ++j) {
                float v = acc[i][j][r];
                if (MODE == 0 || MODE == 3) Cf[base + j * 16] = v;
                if (MODE == 2) Cs[base + j * 16] = f2bf(v);
                if (MODE == 4) Cf[base + j * 16] = Cf[base + j * 16] + v;
            }
        }
    }
}

// ---------------- combine: dst = add + sum of 4 fp32 slices (float4-vectorized) ----------
__global__ void combine4(const float* __restrict__ slices, const float* __restrict__ add,
                         float* __restrict__ dst) {
    long long i = (long long)blockIdx.x * 256 + threadIdx.x;  // over (TOKENS*DIM)/4
    const long long S4 = (long long)TOKENS * DIM / 4;
    float4 s = ((const float4*)add)[i];
    #pragma unroll
    for (int c = 0; c < 4; ++c) {
        float4 p = ((const float4*)slices)[c * S4 + i];
        s.x += p.x; s.y += p.y; s.z += p.z; s.w += p.w;
    }
    ((float4*)dst)[i] = s;
}

// ---------------- QKV post (bf16 qkv): split heads, l2norm(q,k), RoPE -> bf16 [h][s][64] ----
__global__ __launch_bounds__(256) void qkv_post(const short* __restrict__ qkv,
                                                short* __restrict__ q,
                                                short* __restrict__ k) {
    int lane = threadIdx.x & 63;
    int sh = blockIdx.x * 4 + (threadIdx.x >> 6);
    int s = sh >> 4;
    int h = sh & 15;
    const short* base = qkv + (long long)s * 3 * DIM;
    float qv = bf2f(base[h * HEADDIM + lane]);
    float kv = bf2f(base[DIM + h * HEADDIM + lane]);
    float qs = qv * qv, ks = kv * kv;
    #pragma unroll
    for (int off = 32; off; off >>= 1) {
        qs += __shfl_xor(qs, off);
        ks += __shfl_xor(ks, off);
    }
    qv /= fmaxf(sqrtf(qs), EPS_);
    kv /= fmaxf(sqrtf(ks), EPS_);
    int i = lane & 31;
    float f = (float)s * powf(10000.0f, -(float)i / 32.0f);
    float c = cosf(f), sn = sinf(f);
    float qo = __shfl_xor(qv, 32);
    float ko = __shfl_xor(kv, 32);
    float sgn = (lane < 32) ? sn : -sn;
    float qr = qv * c + qo * sgn;
    float kr = kv * c + ko * sgn;
    long long o = ((long long)h * TOKENS + s) * HEADDIM + lane;
    q[o] = f2bf(qr);
    k[o] = f2bf(kr);
}

// ---------------- V transpose (bf16 qkv): [s][3D] -> vt bf16 [h][64][2048] ----------------
__global__ __launch_bounds__(256) void vtrans(const short* __restrict__ qkv,
                                              short* __restrict__ vt) {
    int h = blockIdx.z;
    int s0 = blockIdx.x * 32, d0 = blockIdx.y * 32;
    __shared__ short t[32][34];
    int tx = threadIdx.x & 31, ty = threadIdx.x >> 5;
    #pragma unroll
    for (int r = ty; r < 32; r += 8)
        t[r][tx] = qkv[(long long)(s0 + r) * (3 * DIM) + 2 * DIM + h * HEADDIM + d0 + tx];
    __syncthreads();
    #pragma unroll
    for (int r = ty; r < 32; r += 8)
        vt[((long long)h * HEADDIM + d0 + r) * TOKENS + s0 + tx] = t[tx][r];
}

// ---------------- MFMA flash attention: LDS-staged K/V (DMA), key-split combine ----------
#define PLD 68
__global__ __launch_bounds__(256) void attn_kernel(const short* __restrict__ q,
                                                   const short* __restrict__ k,
                                                   const short* __restrict__ vt,
                                                   float* __restrict__ Oacc,
                                                   float* __restrict__ lacc) {
    const int w = threadIdx.x >> 6, lane = threadIdx.x & 63;
    const int col = lane & 15, quad = lane >> 4;
    const int head = blockIdx.x / 80;
    const int t = blockIdx.x % 80;
    int qb, ch;
    if (t < 8)       { qb = t;                ch = 0; }
    else if (t < 24) { qb = 8 + (t - 8) / 2;  ch = (t - 8) % 2; }
    else if (t < 48) { qb = 16 + (t - 24) / 3; ch = (t - 24) % 3; }
    else             { qb = 24 + (t - 48) / 4; ch = (t - 48) % 4; }
    const int nch = qb / 8 + 1;
    const int ntk = qb + 1;
    const int per = (ntk + nch - 1) / nch;
    const int t0 = ch * per;
    const int t1 = (t0 + per < ntk) ? t0 + per : ntk;
    const int qbase = qb * 64 + w * 16;
    __shared__ short Ks[64 * 64];
    __shared__ short Vs[64 * 64];
    __shared__ short Ps[4 * 16 * PLD];
    short* Pw = Ps + w * 16 * PLD;
    const short* kh = k + (long long)head * TOKENS * HEADDIM;
    const short* vh = vt + (long long)head * HEADDIM * TOKENS;
    const int r8 = lane >> 3;
    const int sw = ((lane & 7) ^ r8) * 8;     // swizzled source col, shorts
    bf8 qf[2];
    #pragma unroll
    for (int ks = 0; ks < 2; ++ks)
        qf[ks] = *(const bf8*)(q + ((long long)head * TOKENS + qbase + col) * HEADDIM + ks * 32 + quad * 8);
    const int fo0 = (((0 * 4) + quad) ^ (col & 7)) * 8;
    const int fo1 = (((1 * 4) + quad) ^ (col & 7)) * 8;
    f32x4 o_[4];
    float l_[4];
    #pragma unroll
    for (int n = 0; n < 4; ++n) { f32x4 z = {0.f, 0.f, 0.f, 0.f}; o_[n] = z; }
    #pragma unroll
    for (int r = 0; r < 4; ++r) l_[r] = 0.f;
    for (int kt = t0; kt < t1; ++kt) {
        const int j0 = kt * 64;
        #pragma unroll
        for (int c = 0; c < 2; ++c) {
            int row = w * 16 + c * 8 + r8;
            async16(kh + (long long)(j0 + row) * HEADDIM + sw, Ks + (w * 16 + c * 8) * 64 + lane * 8);
            async16(vh + (long long)row * TOKENS + j0 + sw, Vs + (w * 16 + c * 8) * 64 + lane * 8);
        }
        __syncthreads();
        f32x4 sacc[4];
        #pragma unroll
        for (int n = 0; n < 4; ++n) { f32x4 z = {0.f, 0.f, 0.f, 0.f}; sacc[n] = z; }
        #pragma unroll
        for (int ks = 0; ks < 2; ++ks) {
            const int fo = ks ? fo1 : fo0;
            #pragma unroll
            for (int nt = 0; nt < 4; ++nt) {
                bf8 kf = *(const bf8*)(Ks + (nt * 16 + col) * 64 + fo);
                sacc[nt] = __builtin_amdgcn_mfma_f32_16x16x32_bf16(qf[ks], kf, sacc[nt], 0, 0, 0);
            }
        }
        const bool diag = (j0 + 64 > qbase);
        #pragma unroll
        for (int nt = 0; nt < 4; ++nt)
            #pragma unroll
            for (int r = 0; r < 4; ++r) {
                float p = __expf(sacc[nt][r] * 0.125f);
                if (diag && (j0 + nt * 16 + col > qbase + quad * 4 + r)) p = 0.f;
                l_[r] += p;
                Pw[(quad * 4 + r) * PLD + nt * 16 + col] = f2bf(p);
            }
        #pragma unroll
        for (int ks = 0; ks < 2; ++ks) {
            bf8 pf = *(const bf8*)(Pw + col * PLD + ks * 32 + quad * 8);
            const int fo = ks ? fo1 : fo0;
            #pragma unroll
            for (int nt = 0; nt < 4; ++nt) {
                bf8 vf = *(const bf8*)(Vs + (nt * 16 + col) * 64 + fo);
                o_[nt] = __builtin_amdgcn_mfma_f32_16x16x32_bf16(pf, vf, o_[nt], 0, 0, 0);
            }
        }
        __syncthreads();
    }
    float* Oc = Oacc + (long long)ch * (TOKENS * DIM);
    #pragma unroll
    for (int r = 0; r < 4; ++r) {
        int row = qbase + quad * 4 + r;
        float* op = Oc + (long long)row * DIM + head * HEADDIM;
        #pragma unroll
        for (int nt = 0; nt < 4; ++nt)
            op[nt * 16 + col] = o_[nt][r];
        float l = l_[r];
        #pragma unroll
        for (int off = 1; off < 16; off <<= 1) l += __shfl_xor(l, off);
        if (col == 0) lacc[ch * (TOKENS * NHEADS) + row * NHEADS + head] = l;
    }
}

// ---------------- Attention normalize: xo = sum_ch Oacc / sum_ch l -> bf16 ----------------
__global__ void attn_norm(const float* __restrict__ Oacc, const float* __restrict__ lacc,
                          short* __restrict__ xo) {
    long long i = (long long)blockIdx.x * 256 + threadIdx.x;  // 2M
    int row = (int)(i >> 10), col = (int)(i & 1023);
    int nch = (row >> 9) + 1;                // (row/64)/8 + 1
    int head = col >> 6;
    float so = 0.f, sl = 0.f;
    for (int c = 0; c < nch; ++c) {
        so += Oacc[(long long)c * (TOKENS * DIM) + i];
        sl += lacc[c * (TOKENS * NHEADS) + row * NHEADS + head];
    }
    xo[i] = f2bf(so / sl);
}

// ---------------- Router (bf16 x input) ----------------
__global__ __launch_bounds__(256) void router_kernel(const short* __restrict__ xf,
                                                     const float* __restrict__ keys_w,
                                                     const int* __restrict__ idx,
                                                     const float* __restrict__ vals,
                                                     float* __restrict__ w_route) {
    int t = blockIdx.x;
    int tid = threadIdx.x;
    int e = tid & 31, c = tid >> 5;
    const short* xr = xf + (long long)t * DIM;
    float p = 0.f;
    for (int j = 0; j < 128; ++j)
        p += bf2f(xr[c * 128 + j]) * keys_w[(c * 128 + j) * NEXP + e];
    __shared__ float part[8][32];
    part[c][e] = p;
    __syncthreads();
    if (tid < NEXP) {
        float lg = 0.f;
        #pragma unroll
        for (int cc = 0; cc < 8; ++cc) lg += part[cc][tid];
        part[0][tid] = lg;
    }
    __syncthreads();
    __shared__ float gate_s[TOPK];
    __shared__ int idx_s[TOPK];
    if (tid < TOPK) {
        int ii = idx[t * TOPK + tid];
        float g = vals[t * TOPK + tid] + part[0][ii];
        gate_s[tid] = (1.0f / (1.0f + __expf(-g))) * RSF_;
        idx_s[tid] = ii;
    }
    __syncthreads();
    if (tid < NEXP) {
        float wr = 0.f;
        #pragma unroll
        for (int kk = 0; kk < TOPK; ++kk)
            if (idx_s[kk] == tid) wr += gate_s[kk];
        w_route[(long long)t * NEXP + tid] = wr;
    }
}

// ---------------- h = silu(g) * u * w_route -> bf16 (gu bf16 [t][e*256 + {g:0-127,u:128-255}]) --
__global__ void moe_act_kernel(const short* __restrict__ gu, const float* __restrict__ w_route,
                               short* __restrict__ hb) {
    long long i = (long long)blockIdx.x * 256 + threadIdx.x;  // 8M = T*NEXP*EDIM
    int t = (int)(i >> 12);
    int e = (int)(i >> 7) & 31;
    int j = (int)(i & 127);
    float gv = bf2f(gu[(long long)t * (NEXP * 256) + e * 256 + j]);
    float uv = bf2f(gu[(long long)t * (NEXP * 256) + e * 256 + 128 + j]);
    float w = w_route[t * NEXP + e];
    float si = gv / (1.0f + __expf(-gv));
    hb[i] = f2bf(si * uv * w);
}

// ---------------- Shared-expert SwiGLU (bf16 in) -> bf16 ----------------
__global__ void swiglu_kernel(const short* __restrict__ up, short* __restrict__ hs) {
    long long i = (long long)blockIdx.x * 256 + threadIdx.x;  // 4M
    int t = (int)(i >> 11), j = (int)(i & 2047);
    float x1 = bf2f(up[(long long)t * (2 * DSHARED) + j]);
    float x2 = bf2f(up[(long long)t * (2 * DSHARED) + DSHARED + j]);
    hs[i] = f2bf(x1 / (1.0f + __expf(-x1)) * x2);
}

extern "C" void kernel_launch(void* const* d_in, const int* in_sizes, int n_in,
                              void* d_out, int out_size, void* d_ws, size_t ws_size,
                              hipStream_t stream) {
    (void)in_sizes; (void)n_in; (void)out_size; (void)ws_size;
    const float* x_input     = (const float*)d_in[0];
    const int*   indices     = (const int*)d_in[1];
    const float* values      = (const float*)d_in[2];
    const float* w_attn      = (const float*)d_in[3];
    const float* w_attn_o    = (const float*)d_in[4];
    const float* attn_norm_w = (const float*)d_in[5];
    const float* ffn_norm_w  = (const float*)d_in[6];
    const float* ffn_experts = (const float*)d_in[7];
    const float* keys_w      = (const float*)d_in[8];
    const float* w_up        = (const float*)d_in[9];
    const float* w_down      = (const float*)d_in[10];
    float* out = (float*)d_out;
    float* ws  = (float*)d_ws;

    const long long M1 = 1024 * 1024;
    const long long SLICE = (long long)TOKENS * DIM;  // 2M floats
    // Workspace (float units, lifetime-aliased; max extent 24M floats = 96MB):
    float* xffn    = ws + 0 * M1;                     // [0,2)   x_input + attn_o
    short* xa_bf   = (short*)(ws + 4 * M1);           // [4,4.5)
    short* xf_bf   = (short*)(ws + 4 * M1 + M1 / 2);  // [4.5,5)
    short* xattn_bf= (short*)(ws + 5 * M1);           // [5,5.5)
    float* w_route = ws + 5 * M1 + M1 / 2;            // [5.5,5.6)
    short* qkv_bf  = (short*)(ws + 6 * M1);           // [6,9)    dead after vtrans
    float* Oacc    = ws + 6 * M1;                     // [6,14)   4 partial O slices (reuses qkv)
    float* lacc    = ws + 14 * M1;                    // [14,14.125)
    short* qh_bf   = (short*)(ws + 15 * M1);          // [15,15.5)
    short* kh_bf   = (short*)(ws + 15 * M1 + M1 / 2); // [15.5,16)
    short* vt_bf   = (short*)(ws + 16 * M1);          // [16,16.5)
    short* wattn_t = (short*)(ws + 17 * M1);          // [17,18.5)
    short* wattno_t= (short*)(ws + 18 * M1 + M1 / 2); // [18.5,19)
    float* oslice  = ws + 6 * M1;                     // [6,14)   attn-o K-split slices (Oacc dead)
    short* wgu     = (short*)(ws + 6 * M1);           // [6,10)   phase B (oslice dead after combine)
    short* gu_bf   = (short*)(ws + 10 * M1);          // [10,18)
    short* h_bf    = (short*)(ws + 18 * M1);          // [18,22)
    short* w2t     = (short*)(ws + 22 * M1);          // [22,24)
    float* yslice  = ws + 6 * M1;                     // [6,14)   w2+down K-split slices (wgu dead)
    short* wupt    = (short*)(ws + 14 * M1);          // [14,16)  phase C (gu_bf dead)
    short* up_bf   = (short*)(ws + 16 * M1);          // [16,20)  (h_bf dead)
    short* hs_bf   = (short*)(ws + 20 * M1);          // [20,22)
    short* wdownt  = (short*)(ws + 22 * M1);          // [22,23)  (w2t dead)

    const long long EXP_STRIDE = (long long)NEXP * DIM * EDIM;  // 4M

    // ---- phase A: attention ----
    tconv<<<dim3(3072 / 32, DIM / 32, 1), 256, 0, stream>>>(w_attn, 0, wattn_t, 0, DIM, 3 * DIM);
    rmsnorm_kernel<<<TOKENS, 256, 0, stream>>>(x_input, attn_norm_w, xa_bf);
    gemm_bf16<2><<<dim3(3072 / 128, TOKENS / 128, 1), 256, 0, stream>>>(
        xa_bf, DIM, 0, wattn_t, DIM, 0, qkv_bf, 3 * DIM, 0, TOKENS, 3 * DIM, DIM);
    qkv_post<<<(TOKENS * NHEADS) / 4, 256, 0, stream>>>(qkv_bf, qh_bf, kh_bf);
    vtrans<<<dim3(TOKENS / 32, HEADDIM / 32, NHEADS), 256, 0, stream>>>(qkv_bf, vt_bf);
    attn_kernel<<<NHEADS * 80, 256, 0, stream>>>(qh_bf, kh_bf, vt_bf, Oacc, lacc);
    attn_norm<<<(TOKENS * DIM) / 256, 256, 0, stream>>>(Oacc, lacc, xattn_bf);
    tconv<<<dim3(DIM / 32, DIM / 32, 1), 256, 0, stream>>>(w_attn_o, 0, wattno_t, 0, DIM, DIM);
    // attn-o GEMM: K-split into 4 fp32 slices (plain stores), combine with residual
    gemm_bf16<3><<<dim3(DIM / 128, TOKENS / 128, 4), 256, 0, stream>>>(
        xattn_bf, DIM, 0, wattno_t, DIM, 0, oslice, DIM, SLICE, TOKENS, DIM, DIM);
    combine4<<<(TOKENS * DIM) / 1024, 256, 0, stream>>>(oslice, x_input, xffn);

    // ---- phase B: router + experts ----
    rmsnorm_kernel<<<TOKENS, 256, 0, stream>>>(xffn, ffn_norm_w, xf_bf);
    router_kernel<<<TOKENS, 256, 0, stream>>>(xf_bf, keys_w, indices, values, w_route);
    // Wgu[e] = [256][1024]: rows 0-127 = W0[e]^T, 128-255 = W1[e]^T
    tconv<<<dim3(EDIM / 32, DIM / 32, NEXP), 256, 0, stream>>>(
        ffn_experts, (long long)DIM * EDIM, wgu, 256 * 1024, DIM, EDIM);
    tconv<<<dim3(EDIM / 32, DIM / 32, NEXP), 256, 0, stream>>>(
        ffn_experts + EXP_STRIDE, (long long)DIM * EDIM, wgu + 128 * 1024, 256 * 1024, DIM, EDIM);
    gemm_bf16<2><<<dim3(2, TOKENS / 128, NEXP), 256, 0, stream>>>(
        xf_bf, DIM, 0, wgu, DIM, 256 * 1024, gu_bf, NEXP * 256, 256, TOKENS, 256, DIM);
    moe_act_kernel<<<(TOKENS * NEXP * EDIM) / 256, 256, 0, stream>>>(gu_bf, w_route, h_bf);
    w2conv<<<(NEXP * DIM * EDIM) / 256, 256, 0, stream>>>(ffn_experts + 2 * EXP_STRIDE, w2t);
    // w2 down-proj: K-split into 4 fp32 slices (plain stores)
    gemm_bf16<3><<<dim3(DIM / 128, TOKENS / 128, 4), 256, 0, stream>>>(
        h_bf, NEXP * EDIM, 0, w2t, NEXP * EDIM, 0, yslice, DIM, SLICE, TOKENS, DIM, NEXP * EDIM);

    // ---- phase C: shared expert ----
    tconv<<<dim3((2 * DSHARED) / 32, DIM / 32, 1), 256, 0, stream>>>(w_up, 0, wupt, 0, DIM, 2 * DSHARED);
    gemm_bf16<2><<<dim3((2 * DSHARED) / 128, TOKENS / 128, 1), 256, 0, stream>>>(
        xf_bf, DIM, 0, wupt, DIM, 0, up_bf, 2 * DSHARED, 0, TOKENS, 2 * DSHARED, DIM);
    swiglu_kernel<<<(TOKENS * DSHARED) / 256, 256, 0, stream>>>(up_bf, hs_bf);
    tconv<<<dim3(DIM / 32, DSHARED / 32, 1), 256, 0, stream>>>(w_down, 0, wdownt, 0, DSHARED, DIM);
    // shared down-proj: K-split, accumulate into the SAME slices (block-exclusive
    // read+add+store; stream-ordered after w2 GEMM, no atomics)
    gemm_bf16<4><<<dim3(DIM / 128, TOKENS / 128, 4), 256, 0, stream>>>(
        hs_bf, DSHARED, 0, wdownt, DSHARED, 0, yslice, DIM, SLICE, TOKENS, DIM, DSHARED);

    // ---- final: out = xffn + sum of 4 slices ----
    combine4<<<(TOKENS * DIM) / 1024, 256, 0, stream>>>(yslice, xffn, out);
}

// Round 11
// 420.664 us; speedup vs baseline: 1.2887x; 1.0568x over previous
//
#include <hip/hip_runtime.h>
#include <math.h>

#define TOKENS 2048
#define DIM 1024
#define NHEADS 16
#define HEADDIM 64
#define NEXP 32
#define EDIM 128
#define TOPK 8
#define DSHARED 2048
#define RSF_ 2.5f
#define EPS_ 1e-6f

using bf8  = __attribute__((ext_vector_type(8))) short;   // 8 bf16 in 4 VGPRs
using f32x4 = __attribute__((ext_vector_type(4))) float;  // MFMA accumulator

__device__ __forceinline__ short f2bf(float f) {
    unsigned u = __float_as_uint(f);
    unsigned r = (u + 0x7fffu + ((u >> 16) & 1u)) >> 16;
    return (short)r;
}
__device__ __forceinline__ float bf2f(short s) {
    return __uint_as_float(((unsigned)(unsigned short)s) << 16);
}

// Direct global->LDS DMA, 16B per lane. LDS dest = wave-uniform base + lane*16.
__device__ __forceinline__ void async16(const short* g, const short* l) {
    __builtin_amdgcn_global_load_lds(
        (const __attribute__((address_space(1))) void*)(unsigned long long)g,
        (__attribute__((address_space(3))) void*)(unsigned)(unsigned long long)l,
        16, 0, 0);
}

// ---------------- RMSNorm: one block per token, bf16 output ----------------
__global__ __launch_bounds__(256) void rmsnorm_kernel(const float* __restrict__ x,
                                                      const float* __restrict__ w,
                                                      short* __restrict__ out) {
    int row = blockIdx.x;
    const float* xr = x + (long long)row * DIM;
    int t = threadIdx.x;
    float4 xv = ((const float4*)xr)[t];
    float ss = xv.x*xv.x + xv.y*xv.y + xv.z*xv.z + xv.w*xv.w;
    #pragma unroll
    for (int off = 32; off; off >>= 1) ss += __shfl_down(ss, off);
    __shared__ float warps[4];
    if ((t & 63) == 0) warps[t >> 6] = ss;
    __syncthreads();
    float tot = warps[0] + warps[1] + warps[2] + warps[3];
    float scale = rsqrtf(tot / (float)DIM + EPS_);
    float4 wv = ((const float4*)w)[t];
    short4 o;
    o.x = f2bf(xv.x * scale * wv.x);
    o.y = f2bf(xv.y * scale * wv.y);
    o.z = f2bf(xv.z * scale * wv.z);
    o.w = f2bf(xv.w * scale * wv.w);
    ((short4*)(out + (long long)row * DIM))[t] = o;
}

// ---------------- Transpose + convert: fp32 in[K][N] -> bf16 out[N][K] ----------------
__global__ __launch_bounds__(256) void tconv(const float* __restrict__ in, long long sin,
                                             short* __restrict__ out, long long sout,
                                             int K, int N) {
    in  += (long long)blockIdx.z * sin;
    out += (long long)blockIdx.z * sout;
    __shared__ float t[32][33];
    int n0 = blockIdx.x * 32, k0 = blockIdx.y * 32;
    int tx = threadIdx.x & 31, ty = threadIdx.x >> 5;  // ty 0..7
    #pragma unroll
    for (int r = ty; r < 32; r += 8)
        t[r][tx] = in[(long long)(k0 + r) * N + n0 + tx];
    __syncthreads();
    #pragma unroll
    for (int r = ty; r < 32; r += 8)
        out[(long long)(n0 + r) * K + k0 + tx] = f2bf(t[tx][r]);
}

// W2 [e][d][h] fp32 -> bf16 [d][(e*128+h)]
__global__ void w2conv(const float* __restrict__ in, short* __restrict__ out) {
    long long i = (long long)blockIdx.x * 256 + threadIdx.x;  // 4M
    int e = (int)(i >> 17);
    int d = (int)(i >> 7) & 1023;
    int h = (int)(i & 127);
    out[(long long)d * (NEXP * EDIM) + e * EDIM + h] = f2bf(in[i]);
}

// W0/W1 [e][k=0..1023][c=0..127] fp32 -> wgu'[e] rows rr=(c>>4)*32+half*16+(c&15), col k
__global__ __launch_bounds__(256) void guconv(const float* __restrict__ ex,
                                              short* __restrict__ wgu) {
    int z = blockIdx.z;            // 0..63
    int e = z & 31, hf = z >> 5;
    const float* in = ex + (long long)hf * (NEXP * DIM * EDIM) + (long long)e * (DIM * EDIM);
    short* outp = wgu + (long long)e * (256 * 1024);
    __shared__ float t[32][33];
    int n0 = blockIdx.x * 32, k0 = blockIdx.y * 32;
    int tx = threadIdx.x & 31, ty = threadIdx.x >> 5;
    #pragma unroll
    for (int r = ty; r < 32; r += 8)
        t[r][tx] = in[(long long)(k0 + r) * EDIM + n0 + tx];
    __syncthreads();
    #pragma unroll
    for (int r = ty; r < 32; r += 8) {
        int c = n0 + r;
        int rr = ((c >> 4) << 5) + hf * 16 + (c & 15);
        outp[(long long)rr * 1024 + k0 + tx] = f2bf(t[tx][r]);
    }
}

// w_up [1024][4096] fp32 -> wupt' interleaved rows: for logical col n:
// half=n>>11, c2=n&2047, b=c2>>7, cl=c2&127 -> rr = b*256+(cl>>4)*32+half*16+(cl&15)
__global__ __launch_bounds__(256) void upconv(const float* __restrict__ in,
                                              short* __restrict__ outp) {
    __shared__ float t[32][33];
    int n0 = blockIdx.x * 32, k0 = blockIdx.y * 32;
    int tx = threadIdx.x & 31, ty = threadIdx.x >> 5;
    #pragma unroll
    for (int r = ty; r < 32; r += 8)
        t[r][tx] = in[(long long)(k0 + r) * (2 * DSHARED) + n0 + tx];
    __syncthreads();
    #pragma unroll
    for (int r = ty; r < 32; r += 8) {
        int n = n0 + r;
        int hf = n >> 11, c2 = n & 2047;
        int rr = ((c2 >> 7) << 8) + (((c2 & 127) >> 4) << 5) + hf * 16 + (c2 & 15);
        outp[(long long)rr * 1024 + k0 + tx] = f2bf(t[tx][r]);
    }
}

// ---------------- bf16 MFMA GEMM: C[M][N] = A[M][K] @ Bt[N][K]^T ----------------
// 128x128 tile, BK=64, XOR-swizzled LDS, async global->LDS staging.
// MODE 2: bf16 store, z = batch.
// MODE 3: f32 store, z = K-split slice (sC = slice stride). No atomics.
// MODE 4: f32 read+add+store, z = K-split slice (block-exclusive tiles).
template<int MODE>
__global__ __launch_bounds__(256) void gemm_bf16(const short* __restrict__ A, int lda, long long sA,
                                                 const short* __restrict__ Bt, int ldb, long long sBt,
                                                 void* __restrict__ Cv, int ldc, long long sC,
                                                 int M, int N, int K) {
    int koff = 0, Ksub = K;
    if (MODE >= 3) {
        Ksub = K / gridDim.z;
        koff = blockIdx.z * Ksub;
    } else {
        A  += (long long)blockIdx.z * sA;
        Bt += (long long)blockIdx.z * sBt;
    }
    float* Cf = (float*)Cv;
    short* Cs = (short*)Cv;
    Cf += (long long)blockIdx.z * sC;
    Cs += (long long)blockIdx.z * sC;
    const int m0 = blockIdx.y * 128, n0 = blockIdx.x * 128;
    __shared__ short As[128 * 64];
    __shared__ short Bs[128 * 64];
    const int tid = threadIdx.x, lane = tid & 63, w = tid >> 6;
    const int wm = (w >> 1) * 64, wn = (w & 1) * 64;
    const int drow = lane >> 3;
    const int dcol = ((lane & 7) ^ drow) * 8;
    const short* ag = A + (long long)(m0 + w * 32 + drow) * lda + koff + dcol;
    const short* bg = Bt + (long long)(n0 + w * 32 + drow) * ldb + koff + dcol;
    const short* lA = As + w * 32 * 64;
    const short* lB = Bs + w * 32 * 64;
    f32x4 acc[4][4];
    #pragma unroll
    for (int i = 0; i < 4; ++i)
        #pragma unroll
        for (int j = 0; j < 4; ++j) { f32x4 z = {0.f, 0.f, 0.f, 0.f}; acc[i][j] = z; }
    const int ra = lane & 15, quad = lane >> 4;
    const int fs0 = ((quad + 0) ^ (ra & 7)) * 8;
    const int fs1 = ((quad + 4) ^ (ra & 7)) * 8;
    for (int k0 = 0; k0 < Ksub; k0 += 64) {
        #pragma unroll
        for (int c = 0; c < 4; ++c) {
            async16(ag + (long long)(c * 8) * lda + k0, lA + c * 512);
            async16(bg + (long long)(c * 8) * ldb + k0, lB + c * 512);
        }
        __syncthreads();
        #pragma unroll
        for (int h = 0; h < 2; ++h) {
            const int fs = h ? fs1 : fs0;
            bf8 af[4], bfv[4];
            #pragma unroll
            for (int i = 0; i < 4; ++i) af[i]  = *(const bf8*)(As + (wm + i * 16 + ra) * 64 + fs);
            #pragma unroll
            for (int j = 0; j < 4; ++j) bfv[j] = *(const bf8*)(Bs + (wn + j * 16 + ra) * 64 + fs);
            #pragma unroll
            for (int i = 0; i < 4; ++i)
                #pragma unroll
                for (int j = 0; j < 4; ++j)
                    acc[i][j] = __builtin_amdgcn_mfma_f32_16x16x32_bf16(af[i], bfv[j], acc[i][j], 0, 0, 0);
        }
        __syncthreads();
    }
    const int cr = quad * 4, cc = ra;
    #pragma unroll
    for (int i = 0; i < 4; ++i) {
        #pragma unroll
        for (int r = 0; r < 4; ++r) {
            int row = m0 + wm + i * 16 + cr + r;
            long long base = (long long)row * ldc + n0 + wn + cc;
            #pragma unroll
            for (int j = 0; j < 4; ++j) {
                float v = acc[i][j][r];
                if (MODE == 2) Cs[base + j * 16] = f2bf(v);
                if (MODE == 3) Cf[base + j * 16] = v;
                if (MODE == 4) Cf[base + j * 16] = Cf[base + j * 16] + v;
            }
        }
    }
}

// ---------------- Fused GEMM + gated activation ----------------
// A[M=2048][K=1024] bf16 @ 256-row interleaved weight blocks; epilogue computes
// silu(g)*u(*w_route) register-locally (g/u pairs in adjacent j regs) and
// writes 128 bf16 cols per block. Tile: 64 M-rows x 256 weight rows, BK=64.
// gu:  grid (1, 32, 32): Bp = wgu + z*sBt,  cols z*128, scale = w_route[t][z]
// up:  grid (16, 32, 1): Bp = wupt + x*256K, cols x*128, no scale
template<bool SCALED>
__global__ __launch_bounds__(256) void gemm_act(const short* __restrict__ A, int lda,
                                                const short* __restrict__ Bt, long long sBt,
                                                short* __restrict__ Ct, int ldct,
                                                const float* __restrict__ wr) {
    const short* Bp = Bt + (long long)blockIdx.z * sBt + (long long)blockIdx.x * (256 * 1024);
    const int cb = (blockIdx.z * gridDim.x + blockIdx.x) * 128;
    const int m0 = blockIdx.y * 64;
    __shared__ short As[64 * 64];
    __shared__ short Bs[256 * 64];
    const int tid = threadIdx.x, lane = tid & 63, w = tid >> 6;
    const int wm = (w >> 1) * 32, wn = (w & 1) * 128;
    const int drow = lane >> 3;
    const int dcol = ((lane & 7) ^ drow) * 8;
    const short* ag = A + (long long)(m0 + w * 16 + drow) * lda + dcol;
    const short* bg = Bp + (long long)(w * 64 + drow) * 1024 + dcol;
    const short* lA = As + w * 16 * 64;
    const short* lB = Bs + w * 64 * 64;
    f32x4 acc[2][8];
    #pragma unroll
    for (int i = 0; i < 2; ++i)
        #pragma unroll
        for (int j = 0; j < 8; ++j) { f32x4 z = {0.f, 0.f, 0.f, 0.f}; acc[i][j] = z; }
    const int ra = lane & 15, quad = lane >> 4;
    const int fs0 = ((quad + 0) ^ (ra & 7)) * 8;
    const int fs1 = ((quad + 4) ^ (ra & 7)) * 8;
    for (int k0 = 0; k0 < 1024; k0 += 64) {
        async16(ag + k0, lA);
        async16(ag + (long long)8 * lda + k0, lA + 512);
        #pragma unroll
        for (int c = 0; c < 8; ++c)
            async16(bg + (long long)(c * 8) * 1024 + k0, lB + c * 512);
        __syncthreads();
        #pragma unroll
        for (int h = 0; h < 2; ++h) {
            const int fs = h ? fs1 : fs0;
            bf8 af0 = *(const bf8*)(As + (wm + ra) * 64 + fs);
            bf8 af1 = *(const bf8*)(As + (wm + 16 + ra) * 64 + fs);
            #pragma unroll
            for (int j = 0; j < 8; ++j) {
                bf8 bv = *(const bf8*)(Bs + (wn + j * 16 + ra) * 64 + fs);
                acc[0][j] = __builtin_amdgcn_mfma_f32_16x16x32_bf16(af0, bv, acc[0][j], 0, 0, 0);
                acc[1][j] = __builtin_amdgcn_mfma_f32_16x16x32_bf16(af1, bv, acc[1][j], 0, 0, 0);
            }
        }
        __syncthreads();
    }
    // epilogue: rows wn+j*16+ra are weight rows rr; pair (j even = g, j odd = u);
    // output col = cb + wn/2 + (j>>1)*16 + ra
    #pragma unroll
    for (int i = 0; i < 2; ++i)
        #pragma unroll
        for (int r = 0; r < 4; ++r) {
            int token = m0 + wm + i * 16 + quad * 4 + r;
            float scale = SCALED ? wr[token * NEXP + blockIdx.z] : 1.0f;
            #pragma unroll
            for (int jp = 0; jp < 4; ++jp) {
                float g = acc[i][2 * jp][r];
                float u = acc[i][2 * jp + 1][r];
                float v = g / (1.0f + __expf(-g)) * u * scale;
                Ct[(long long)token * ldct + cb + wn / 2 + jp * 16 + ra] = f2bf(v);
            }
        }
}

// ---------------- combine: dst = add + sum of 4 fp32 slices ----------------
__global__ void combine4(const float* __restrict__ slices, const float* __restrict__ add,
                         float* __restrict__ dst) {
    long long i = (long long)blockIdx.x * 256 + threadIdx.x;
    const long long S4 = (long long)TOKENS * DIM / 4;
    float4 s = ((const float4*)add)[i];
    #pragma unroll
    for (int c = 0; c < 4; ++c) {
        float4 p = ((const float4*)slices)[c * S4 + i];
        s.x += p.x; s.y += p.y; s.z += p.z; s.w += p.w;
    }
    ((float4*)dst)[i] = s;
}

// ---------------- combine 4 slices + residual -> xffn fp32 AND rmsnorm -> bf16 -------
__global__ __launch_bounds__(256) void combine_rms(const float* __restrict__ slices,
                                                   const float* __restrict__ add,
                                                   const float* __restrict__ w,
                                                   float* __restrict__ xffn,
                                                   short* __restrict__ xf) {
    int row = blockIdx.x, t = threadIdx.x;
    long long i = (long long)row * 256 + t;
    const long long S4 = (long long)TOKENS * DIM / 4;
    float4 s = ((const float4*)add)[i];
    #pragma unroll
    for (int c = 0; c < 4; ++c) {
        float4 p = ((const float4*)slices)[c * S4 + i];
        s.x += p.x; s.y += p.y; s.z += p.z; s.w += p.w;
    }
    ((float4*)xffn)[i] = s;
    float ss = s.x*s.x + s.y*s.y + s.z*s.z + s.w*s.w;
    #pragma unroll
    for (int off = 32; off; off >>= 1) ss += __shfl_down(ss, off);
    __shared__ float warps[4];
    if ((t & 63) == 0) warps[t >> 6] = ss;
    __syncthreads();
    float tot = warps[0] + warps[1] + warps[2] + warps[3];
    float scale = rsqrtf(tot / (float)DIM + EPS_);
    float4 wv = ((const float4*)w)[t];
    short4 o;
    o.x = f2bf(s.x * scale * wv.x);
    o.y = f2bf(s.y * scale * wv.y);
    o.z = f2bf(s.z * scale * wv.z);
    o.w = f2bf(s.w * scale * wv.w);
    ((short4*)(xf + (long long)row * DIM))[t] = o;
}

// ---------------- QKV post (bf16 qkv): split heads, l2norm(q,k), RoPE -> bf16 [h][s][64] ----
__global__ __launch_bounds__(256) void qkv_post(const short* __restrict__ qkv,
                                                short* __restrict__ q,
                                                short* __restrict__ k) {
    int lane = threadIdx.x & 63;
    int sh = blockIdx.x * 4 + (threadIdx.x >> 6);
    int s = sh >> 4;
    int h = sh & 15;
    const short* base = qkv + (long long)s * 3 * DIM;
    float qv = bf2f(base[h * HEADDIM + lane]);
    float kv = bf2f(base[DIM + h * HEADDIM + lane]);
    float qs = qv * qv, ks = kv * kv;
    #pragma unroll
    for (int off = 32; off; off >>= 1) {
        qs += __shfl_xor(qs, off);
        ks += __shfl_xor(ks, off);
    }
    qv /= fmaxf(sqrtf(qs), EPS_);
    kv /= fmaxf(sqrtf(ks), EPS_);
    int i = lane & 31;
    float f = (float)s * powf(10000.0f, -(float)i / 32.0f);
    float c = cosf(f), sn = sinf(f);
    float qo = __shfl_xor(qv, 32);
    float ko = __shfl_xor(kv, 32);
    float sgn = (lane < 32) ? sn : -sn;
    float qr = qv * c + qo * sgn;
    float kr = kv * c + ko * sgn;
    long long o = ((long long)h * TOKENS + s) * HEADDIM + lane;
    q[o] = f2bf(qr);
    k[o] = f2bf(kr);
}

// ---------------- V transpose (bf16 qkv): [s][3D] -> vt bf16 [h][64][2048] ----------------
__global__ __launch_bounds__(256) void vtrans(const short* __restrict__ qkv,
                                              short* __restrict__ vt) {
    int h = blockIdx.z;
    int s0 = blockIdx.x * 32, d0 = blockIdx.y * 32;
    __shared__ short t[32][34];
    int tx = threadIdx.x & 31, ty = threadIdx.x >> 5;
    #pragma unroll
    for (int r = ty; r < 32; r += 8)
        t[r][tx] = qkv[(long long)(s0 + r) * (3 * DIM) + 2 * DIM + h * HEADDIM + d0 + tx];
    __syncthreads();
    #pragma unroll
    for (int r = ty; r < 32; r += 8)
        vt[((long long)h * HEADDIM + d0 + r) * TOKENS + s0 + tx] = t[tx][r];
}

// ---------------- MFMA flash attention: LDS-staged K/V (DMA), key-split combine ----------
#define PLD 68
__global__ __launch_bounds__(256) void attn_kernel(const short* __restrict__ q,
                                                   const short* __restrict__ k,
                                                   const short* __restrict__ vt,
                                                   float* __restrict__ Oacc,
                                                   float* __restrict__ lacc) {
    const int w = threadIdx.x >> 6, lane = threadIdx.x & 63;
    const int col = lane & 15, quad = lane >> 4;
    const int head = blockIdx.x / 80;
    const int t = blockIdx.x % 80;
    int qb, ch;
    if (t < 8)       { qb = t;                ch = 0; }
    else if (t < 24) { qb = 8 + (t - 8) / 2;  ch = (t - 8) % 2; }
    else if (t < 48) { qb = 16 + (t - 24) / 3; ch = (t - 24) % 3; }
    else             { qb = 24 + (t - 48) / 4; ch = (t - 48) % 4; }
    const int nch = qb / 8 + 1;
    const int ntk = qb + 1;
    const int per = (ntk + nch - 1) / nch;
    const int t0 = ch * per;
    const int t1 = (t0 + per < ntk) ? t0 + per : ntk;
    const int qbase = qb * 64 + w * 16;
    __shared__ short Ks[64 * 64];
    __shared__ short Vs[64 * 64];
    __shared__ short Ps[4 * 16 * PLD];
    short* Pw = Ps + w * 16 * PLD;
    const short* kh = k + (long long)head * TOKENS * HEADDIM;
    const short* vh = vt + (long long)head * HEADDIM * TOKENS;
    const int r8 = lane >> 3;
    const int sw = ((lane & 7) ^ r8) * 8;
    bf8 qf[2];
    #pragma unroll
    for (int ks = 0; ks < 2; ++ks)
        qf[ks] = *(const bf8*)(q + ((long long)head * TOKENS + qbase + col) * HEADDIM + ks * 32 + quad * 8);
    const int fo0 = (((0 * 4) + quad) ^ (col & 7)) * 8;
    const int fo1 = (((1 * 4) + quad) ^ (col & 7)) * 8;
    f32x4 o_[4];
    float l_[4];
    #pragma unroll
    for (int n = 0; n < 4; ++n) { f32x4 z = {0.f, 0.f, 0.f, 0.f}; o_[n] = z; }
    #pragma unroll
    for (int r = 0; r < 4; ++r) l_[r] = 0.f;
    for (int kt = t0; kt < t1; ++kt) {
        const int j0 = kt * 64;
        #pragma unroll
        for (int c = 0; c < 2; ++c) {
            int row = w * 16 + c * 8 + r8;
            async16(kh + (long long)(j0 + row) * HEADDIM + sw, Ks + (w * 16 + c * 8) * 64 + lane * 8);
            async16(vh + (long long)row * TOKENS + j0 + sw, Vs + (w * 16 + c * 8) * 64 + lane * 8);
        }
        __syncthreads();
        f32x4 sacc[4];
        #pragma unroll
        for (int n = 0; n < 4; ++n) { f32x4 z = {0.f, 0.f, 0.f, 0.f}; sacc[n] = z; }
        #pragma unroll
        for (int ks = 0; ks < 2; ++ks) {
            const int fo = ks ? fo1 : fo0;
            #pragma unroll
            for (int nt = 0; nt < 4; ++nt) {
                bf8 kf = *(const bf8*)(Ks + (nt * 16 + col) * 64 + fo);
                sacc[nt] = __builtin_amdgcn_mfma_f32_16x16x32_bf16(qf[ks], kf, sacc[nt], 0, 0, 0);
            }
        }
        const bool diag = (j0 + 64 > qbase);
        #pragma unroll
        for (int nt = 0; nt < 4; ++nt)
            #pragma unroll
            for (int r = 0; r < 4; ++r) {
                float p = __expf(sacc[nt][r] * 0.125f);
                if (diag && (j0 + nt * 16 + col > qbase + quad * 4 + r)) p = 0.f;
                l_[r] += p;
                Pw[(quad * 4 + r) * PLD + nt * 16 + col] = f2bf(p);
            }
        #pragma unroll
        for (int ks = 0; ks < 2; ++ks) {
            bf8 pf = *(const bf8*)(Pw + col * PLD + ks * 32 + quad * 8);
            const int fo = ks ? fo1 : fo0;
            #pragma unroll
            for (int nt = 0; nt < 4; ++nt) {
                bf8 vf = *(const bf8*)(Vs + (nt * 16 + col) * 64 + fo);
                o_[nt] = __builtin_amdgcn_mfma_f32_16x16x32_bf16(pf, vf, o_[nt], 0, 0, 0);
            }
        }
        __syncthreads();
    }
    float* Oc = Oacc + (long long)ch * (TOKENS * DIM);
    #pragma unroll
    for (int r = 0; r < 4; ++r) {
        int row = qbase + quad * 4 + r;
        float* op = Oc + (long long)row * DIM + head * HEADDIM;
        #pragma unroll
        for (int nt = 0; nt < 4; ++nt)
            op[nt * 16 + col] = o_[nt][r];
        float l = l_[r];
        #pragma unroll
        for (int off = 1; off < 16; off <<= 1) l += __shfl_xor(l, off);
        if (col == 0) lacc[ch * (TOKENS * NHEADS) + row * NHEADS + head] = l;
    }
}

// ---------------- Attention normalize: xo = sum_ch Oacc / sum_ch l -> bf16 ----------------
__global__ void attn_norm(const float* __restrict__ Oacc, const float* __restrict__ lacc,
                          short* __restrict__ xo) {
    long long i = (long long)blockIdx.x * 256 + threadIdx.x;  // 2M
    int row = (int)(i >> 10), col = (int)(i & 1023);
    int nch = (row >> 9) + 1;
    int head = col >> 6;
    float so = 0.f, sl = 0.f;
    for (int c = 0; c < nch; ++c) {
        so += Oacc[(long long)c * (TOKENS * DIM) + i];
        sl += lacc[c * (TOKENS * NHEADS) + row * NHEADS + head];
    }
    xo[i] = f2bf(so / sl);
}

// ---------------- Router (bf16 x input) ----------------
__global__ __launch_bounds__(256) void router_kernel(const short* __restrict__ xf,
                                                     const float* __restrict__ keys_w,
                                                     const int* __restrict__ idx,
                                                     const float* __restrict__ vals,
                                                     float* __restrict__ w_route) {
    int t = blockIdx.x;
    int tid = threadIdx.x;
    int e = tid & 31, c = tid >> 5;
    const short* xr = xf + (long long)t * DIM;
    float p = 0.f;
    for (int j = 0; j < 128; ++j)
        p += bf2f(xr[c * 128 + j]) * keys_w[(c * 128 + j) * NEXP + e];
    __shared__ float part[8][32];
    part[c][e] = p;
    __syncthreads();
    if (tid < NEXP) {
        float lg = 0.f;
        #pragma unroll
        for (int cc = 0; cc < 8; ++cc) lg += part[cc][tid];
        part[0][tid] = lg;
    }
    __syncthreads();
    __shared__ float gate_s[TOPK];
    __shared__ int idx_s[TOPK];
    if (tid < TOPK) {
        int ii = idx[t * TOPK + tid];
        float g = vals[t * TOPK + tid] + part[0][ii];
        gate_s[tid] = (1.0f / (1.0f + __expf(-g))) * RSF_;
        idx_s[tid] = ii;
    }
    __syncthreads();
    if (tid < NEXP) {
        float wr = 0.f;
        #pragma unroll
        for (int kk = 0; kk < TOPK; ++kk)
            if (idx_s[kk] == tid) wr += gate_s[kk];
        w_route[(long long)t * NEXP + tid] = wr;
    }
}

extern "C" void kernel_launch(void* const* d_in, const int* in_sizes, int n_in,
                              void* d_out, int out_size, void* d_ws, size_t ws_size,
                              hipStream_t stream) {
    (void)in_sizes; (void)n_in; (void)out_size; (void)ws_size;
    const float* x_input     = (const float*)d_in[0];
    const int*   indices     = (const int*)d_in[1];
    const float* values      = (const float*)d_in[2];
    const float* w_attn      = (const float*)d_in[3];
    const float* w_attn_o    = (const float*)d_in[4];
    const float* attn_norm_w = (const float*)d_in[5];
    const float* ffn_norm_w  = (const float*)d_in[6];
    const float* ffn_experts = (const float*)d_in[7];
    const float* keys_w      = (const float*)d_in[8];
    const float* w_up        = (const float*)d_in[9];
    const float* w_down      = (const float*)d_in[10];
    float* out = (float*)d_out;
    float* ws  = (float*)d_ws;

    const long long M1 = 1024 * 1024;
    const long long SLICE = (long long)TOKENS * DIM;  // 2M floats
    // Workspace (float units, lifetime-aliased; max extent 24M floats = 96MB):
    float* xffn    = ws + 0 * M1;                     // [0,2)
    short* xa_bf   = (short*)(ws + 4 * M1);           // [4,4.5)
    short* xf_bf   = (short*)(ws + 4 * M1 + M1 / 2);  // [4.5,5)
    short* xattn_bf= (short*)(ws + 5 * M1);           // [5,5.5)
    float* w_route = ws + 5 * M1 + M1 / 2;            // [5.5,5.6)
    float* Oacc    = ws + 6 * M1;                     // [6,14)   phase A
    float* lacc    = ws + 14 * M1;                    // [14,14.2)
    short* qh_bf   = (short*)(ws + 15 * M1);          // [15,15.5)
    short* kh_bf   = (short*)(ws + 15 * M1 + M1 / 2); // [15.5,16)
    short* vt_bf   = (short*)(ws + 16 * M1);          // [16,16.5)
    short* wattn_t = (short*)(ws + 17 * M1);          // [17,18.5)
    short* wattno_t= (short*)(ws + 18 * M1 + M1 / 2); // [18.5,19)
    short* qkv_bf  = (short*)(ws + 21 * M1);          // [21,24)  dead after vtrans
    float* oslice  = ws + 6 * M1;                     // [6,14)   (Oacc dead after attn_norm)
    short* wgu     = (short*)(ws + 6 * M1);           // [6,10)   phase B (oslice dead)
    short* h_bf    = (short*)(ws + 10 * M1);          // [10,14)
    short* w2t     = (short*)(ws + 14 * M1);          // [14,16)  (lacc dead)
    float* yslice  = ws + 16 * M1;                    // [16,24)  (vt/wattn_t/qkv dead)
    short* wupt    = (short*)(ws + 6 * M1);           // [6,8)    phase C (wgu dead)
    short* hs_bf   = (short*)(ws + 8 * M1);           // [8,10)
    short* wdownt  = (short*)(ws + 10 * M1);          // [10,11)  (h_bf dead)

    // ---- phase A: attention ----
    tconv<<<dim3(3072 / 32, DIM / 32, 1), 256, 0, stream>>>(w_attn, 0, wattn_t, 0, DIM, 3 * DIM);
    rmsnorm_kernel<<<TOKENS, 256, 0, stream>>>(x_input, attn_norm_w, xa_bf);
    gemm_bf16<2><<<dim3(3072 / 128, TOKENS / 128, 1), 256, 0, stream>>>(
        xa_bf, DIM, 0, wattn_t, DIM, 0, qkv_bf, 3 * DIM, 0, TOKENS, 3 * DIM, DIM);
    qkv_post<<<(TOKENS * NHEADS) / 4, 256, 0, stream>>>(qkv_bf, qh_bf, kh_bf);
    vtrans<<<dim3(TOKENS / 32, HEADDIM / 32, NHEADS), 256, 0, stream>>>(qkv_bf, vt_bf);
    attn_kernel<<<NHEADS * 80, 256, 0, stream>>>(qh_bf, kh_bf, vt_bf, Oacc, lacc);
    attn_norm<<<(TOKENS * DIM) / 256, 256, 0, stream>>>(Oacc, lacc, xattn_bf);
    tconv<<<dim3(DIM / 32, DIM / 32, 1), 256, 0, stream>>>(w_attn_o, 0, wattno_t, 0, DIM, DIM);
    gemm_bf16<3><<<dim3(DIM / 128, TOKENS / 128, 4), 256, 0, stream>>>(
        xattn_bf, DIM, 0, wattno_t, DIM, 0, oslice, DIM, SLICE, TOKENS, DIM, DIM);
    // xffn = x_input + sum(oslice); xf_bf = rmsnorm(xffn) -- fused
    combine_rms<<<TOKENS, 256, 0, stream>>>(oslice, x_input, ffn_norm_w, xffn, xf_bf);

    // ---- phase B: router + experts ----
    router_kernel<<<TOKENS, 256, 0, stream>>>(xf_bf, keys_w, indices, values, w_route);
    guconv<<<dim3(EDIM / 32, DIM / 32, 2 * NEXP), 256, 0, stream>>>(ffn_experts, wgu);
    gemm_act<true><<<dim3(1, TOKENS / 64, NEXP), 256, 0, stream>>>(
        xf_bf, DIM, wgu, 256 * 1024, h_bf, NEXP * EDIM, w_route);
    w2conv<<<(NEXP * DIM * EDIM) / 256, 256, 0, stream>>>(
        ffn_experts + 2LL * NEXP * DIM * EDIM, w2t);
    gemm_bf16<3><<<dim3(DIM / 128, TOKENS / 128, 4), 256, 0, stream>>>(
        h_bf, NEXP * EDIM, 0, w2t, NEXP * EDIM, 0, yslice, DIM, SLICE, TOKENS, DIM, NEXP * EDIM);

    // ---- phase C: shared expert ----
    upconv<<<dim3((2 * DSHARED) / 32, DIM / 32, 1), 256, 0, stream>>>(w_up, wupt);
    gemm_act<false><<<dim3((2 * DSHARED) / 256, TOKENS / 64, 1), 256, 0, stream>>>(
        xf_bf, DIM, wupt, 0, hs_bf, DSHARED, nullptr);
    tconv<<<dim3(DIM / 32, DSHARED / 32, 1), 256, 0, stream>>>(w_down, 0, wdownt, 0, DSHARED, DIM);
    gemm_bf16<4><<<dim3(DIM / 128, TOKENS / 128, 4), 256, 0, stream>>>(
        hs_bf, DSHARED, 0, wdownt, DSHARED, 0, yslice, DIM, SLICE, TOKENS, DIM, DSHARED);

    // ---- final: out = xffn + sum of 4 slices ----
    combine4<<<(TOKENS * DIM) / 1024, 256, 0, stream>>>(yslice, xffn, out);
}